// Round 9
// baseline (467.834 us; speedup 1.0000x reference)
//
#include <hip/hip_runtime.h>
#include <stdint.h>

typedef short bf16x8 __attribute__((ext_vector_type(8)));
typedef float f32x4 __attribute__((ext_vector_type(4)));
typedef float f32x16 __attribute__((ext_vector_type(16)));
typedef unsigned short u16;
typedef unsigned int u32;

__device__ __forceinline__ u16 f2bf(float f) {
    u32 x = __float_as_uint(f);
    x += 0x7fffu + ((x >> 16) & 1u);
    return (u16)(x >> 16);
}
__device__ __forceinline__ u32 pack_bf2(float a, float b) {
    return (u32)f2bf(a) | ((u32)f2bf(b) << 16);
}

union Frag4 { u32 u[4]; bf16x8 v; };

// async global->LDS, 16B per lane; LDS dest is wave-uniform base + lane*16
__device__ __forceinline__ void gload16(const u16* g, u16* l) {
    __builtin_amdgcn_global_load_lds(
        (__attribute__((address_space(1))) void*)g,
        (__attribute__((address_space(3))) void*)l,
        16, 0, 0);
}

// ---------------- f32 -> bf16 cast, 8 elems/thread (G13: vectorized) --------
__global__ void cvt_f32_bf16(const float* __restrict__ in, u16* __restrict__ out, long n8) {
    long stride = (long)gridDim.x * blockDim.x;
    for (long i = (long)blockIdx.x * blockDim.x + threadIdx.x; i < n8; i += stride) {
        const float4* p = (const float4*)(in + i * 8);
        float4 a = p[0], b = p[1];
        uint4 o;
        o.x = pack_bf2(a.x, a.y);
        o.y = pack_bf2(a.z, a.w);
        o.z = pack_bf2(b.x, b.y);
        o.w = pack_bf2(b.z, b.w);
        ((uint4*)out)[i] = o;
    }
}

// ---------------- bf16 NT GEMM: out = A * B^T + bias ------------------------
// 128x128 tile, BK=64, 4 waves, dbuf LDS, T4 counted-vmcnt pipeline
// (stage t+2 after compute t, vmcnt(8) mid-loop). Validated round 7.
template<int OBF>
__global__ __launch_bounds__(256, 2) void gemm_nt(
    const u16* __restrict__ A, const u16* __restrict__ B,
    const float* __restrict__ bias, void* __restrict__ out,
    int K, int ldo, int gxsh)
{
    __shared__ __align__(16) u16 lA[2 * 128 * 64];
    __shared__ __align__(16) u16 lB[2 * 128 * 64];
    const int tid  = threadIdx.x;
    const int lane = tid & 63;
    const int w    = tid >> 6;
    const int wm = (w >> 1) * 64, wn = (w & 1) * 64;

    const int nwg = gridDim.x;
    const int bid = blockIdx.x;
    const int swz = (bid & 7) * (nwg >> 3) + (bid >> 3);
    const int bm = (swz & ((1 << gxsh) - 1)) * 128;
    const int bn = (swz >> gxsh) * 128;

    const int lr = lane >> 3;
    const u32 sb = (u32)((lane & 7) * 16);
    const int NT = K >> 6;

    auto stage = [&](int bb, int k0) {
#pragma unroll
        for (int i = 0; i < 4; ++i) {
            const int c = w * 4 + i;
            const int row = c * 8 + lr;
            const u32 col = (sb ^ ((u32)(row & 7) << 4)) >> 1;
            gload16(A + (size_t)(bm + row) * K + k0 + col, lA + bb * 8192 + c * 512);
            gload16(B + (size_t)(bn + row) * K + k0 + col, lB + bb * 8192 + c * 512);
        }
    };

    f32x4 acc[4][4];
#pragma unroll
    for (int i = 0; i < 4; ++i)
#pragma unroll
        for (int j = 0; j < 4; ++j)
#pragma unroll
            for (int r = 0; r < 4; ++r) acc[i][j][r] = 0.f;

    stage(0, 0);
    stage(1, 64);
    asm volatile("s_waitcnt vmcnt(8)" ::: "memory");
    __builtin_amdgcn_sched_barrier(0);
    __builtin_amdgcn_s_barrier();
    __builtin_amdgcn_sched_barrier(0);

    for (int t = 0; t < NT; ++t) {
        const int cur = t & 1;
        const char* pA = (const char*)(lA + cur * 8192);
        const char* pB = (const char*)(lB + cur * 8192);
#pragma unroll
        for (int kk = 0; kk < 2; ++kk) {
            bf16x8 af[4], bfr[4];
#pragma unroll
            for (int f = 0; f < 4; ++f) {
                const int m = wm + f * 16 + (lane & 15);
                const u32 byt = (u32)(kk * 64 + (lane >> 4) * 16) ^ ((u32)(m & 7) << 4);
                af[f]  = *(const bf16x8*)(pA + m * 128 + byt);
                const int n = wn + f * 16 + (lane & 15);
                const u32 bytb = (u32)(kk * 64 + (lane >> 4) * 16) ^ ((u32)(n & 7) << 4);
                bfr[f] = *(const bf16x8*)(pB + n * 128 + bytb);
            }
            __builtin_amdgcn_s_setprio(1);
#pragma unroll
            for (int i = 0; i < 4; ++i)
#pragma unroll
                for (int j = 0; j < 4; ++j)
                    acc[i][j] = __builtin_amdgcn_mfma_f32_16x16x32_bf16(af[i], bfr[j], acc[i][j], 0, 0, 0);
            __builtin_amdgcn_s_setprio(0);
        }
        __builtin_amdgcn_sched_barrier(0);
        __builtin_amdgcn_s_barrier();
        __builtin_amdgcn_sched_barrier(0);
        if (t + 2 < NT) {
            stage(cur, (t + 2) * 64);
            asm volatile("s_waitcnt vmcnt(8)" ::: "memory");
        } else {
            asm volatile("s_waitcnt vmcnt(0)" ::: "memory");
        }
        __builtin_amdgcn_sched_barrier(0);
        __builtin_amdgcn_s_barrier();
        __builtin_amdgcn_sched_barrier(0);
    }

#pragma unroll
    for (int i = 0; i < 4; ++i) {
        int m0 = bm + wm + i * 16 + ((lane >> 4) << 2);
#pragma unroll
        for (int j = 0; j < 4; ++j) {
            int n = bn + wn + j * 16 + (lane & 15);
            float bv = bias[n];
#pragma unroll
            for (int r = 0; r < 4; ++r) {
                float v = acc[i][j][r] + bv;
                if constexpr (OBF != 0)
                    ((u16*)out)[(size_t)(m0 + r) * ldo + n] = f2bf(v);
                else
                    ((float*)out)[(size_t)(m0 + r) * ldo + n] = v;
            }
        }
    }
}

// ---------------- V transpose: vt[b,h,d,t] <- qkv[b*2048+t][4096+h*128+d] ---
__global__ __launch_bounds__(256) void transpose_v(
    const u16* __restrict__ qkv, u16* __restrict__ vt)
{
    __shared__ u16 lt[64 * 64];
    const int tid = threadIdx.x;
    const int bid = blockIdx.x;
    const int tt    = bid & 31;
    const int dtile = (bid >> 5) & 1;
    const int h     = (bid >> 6) & 15;
    const int b     = bid >> 10;
    const u16* src = qkv + ((size_t)b * 2048 + tt * 64) * 6144 + 4096 + h * 128 + dtile * 64;

    const int r = tid >> 2, ce = (tid & 3) * 16;
    uint4 a0 = *(const uint4*)(src + (size_t)r * 6144 + ce);
    uint4 a1 = *(const uint4*)(src + (size_t)r * 6144 + ce + 8);
    const u32 swz = (u32)((r & 7) << 4);
    *(uint4*)((char*)lt + r * 128 + (((u32)(ce * 2)) ^ swz)) = a0;
    *(uint4*)((char*)lt + r * 128 + (((u32)(ce * 2 + 16)) ^ swz)) = a1;
    __syncthreads();

    const int d = tid >> 2;
    u16* dst = vt + ((size_t)(b * 16 + h) * 128 + dtile * 64 + d) * 2048 + tt * 64;
#pragma unroll
    for (int it = 0; it < 2; ++it) {
        const int t0 = (tid & 3) * 8 + it * 32;
        union { u16 hh[8]; uint4 q4; } u;
#pragma unroll
        for (int uu = 0; uu < 8; ++uu) {
            int trow = t0 + uu;
            u32 byt = (u32)(trow * 128) + (((u32)(d * 2)) ^ ((u32)((trow & 7) << 4)));
            u.hh[uu] = *(const u16*)((const char*)lt + byt);
        }
        *(uint4*)(dst + t0) = u.q4;
    }
}

// ---------------- causal flash attention (KVBLK=32, chain-trimmed) ----------
// 768 blocks (KV-split per round 8). KVBLK=32 double-buffered -> 32KB LDS,
// launch_bounds(256,3) to allow 3 blocks/CU. Chain-trim: no per-tile
// cross-half shfl (defer check rides __all; l_run per-lane partial merged
// once after the loop); only the P-exchange shfl round remains.
__constant__ unsigned char QT_TAB[24] = {15,15,7,14,14,13,13,6,12,12,11,11,5,10,10,9,9,4,8,8,3,2,1,0};
__constant__ unsigned char CK_TAB[24] = {0,1,2,0,1,0,1,2,0,1,0,1,2,0,1,0,1,2,0,1,2,2,2,2};

__global__ __launch_bounds__(256, 3) void attn_fwd(
    const u16* __restrict__ qkv, const u16* __restrict__ vt,
    u16* __restrict__ obuf, float* __restrict__ pout, float* __restrict__ pml)
{
    __shared__ __align__(16) u16 lK[2 * 32 * 128];   // [32 kv][128 d] per buf
    __shared__ __align__(16) u16 lV[2 * 128 * 32];   // [128 d][32 kv] per buf
    const int tid  = threadIdx.x;
    const int lane = tid & 63;
    const int w    = tid >> 6;
    const int g    = lane >> 5;
    const int ql   = lane & 31;

    const int bid  = blockIdx.x;
    const int item = bid >> 5;
    const int bh   = bid & 31;
    const int qt   = QT_TAB[item];
    const int ck   = CK_TAB[item];
    const int b = bh >> 4, h = bh & 15;
    const size_t rowbase = (size_t)b * 2048;
    const int qb = qt * 128;
    const int qw = qb + w * 32;
    const int q  = qw + ql;
    // KV tiles of 32: split boundary at 2qt+2 (kv = 64qt+64 <= qb for qt>=1)
    const int t_lo = (ck == 1) ? (2 * qt + 2) : 0;
    const int t_hi = (ck == 0) ? (2 * qt + 2) : (4 * qt + 4);

    const u16* Khead = qkv + rowbase * 6144 + 2048 + h * 128;  // ld 6144
    const u16* Vth   = vt + (size_t)bh * 128 * 2048;           // Vt[d][t]

    bf16x8 qf[8];
    {
        const u16* qrow = qkv + (rowbase + q) * 6144 + h * 128;
#pragma unroll
        for (int ch = 0; ch < 8; ++ch)
            qf[ch] = *(const bf16x8*)(qrow + ch * 16 + g * 8);
    }

    f32x16 acc[4];
#pragma unroll
    for (int dt = 0; dt < 4; ++dt)
#pragma unroll
        for (int r = 0; r < 16; ++r) acc[dt][r] = 0.f;

    float m_run = -1e30f, l_run = 0.f;   // l_run: per-lane partial (own half)
    const float C2 = 0.08838834764831845f * 1.44269504088896341f; // scale*log2e

    // stage 32-kv tile t into buffer bb: per wave 2 K chunks + 2 V chunks
    auto stage = [&](int bb, int t) {
        const int kb = t * 32;
#pragma unroll
        for (int i = 0; i < 2; ++i) {
            const int c = w * 2 + i;                       // 0..7
            // K chunk: 4 rows x 256B
            const int kr = c * 4 + (lane >> 4);            // 0..31
            const u32 kcol = (((u32)((lane & 15) * 16)) ^ ((u32)(kr & 7) << 4)) >> 1;
            gload16(Khead + (size_t)(kb + kr) * 6144 + kcol,
                    lK + bb * 4096 + c * 512);
            // V chunk: 16 rows x 64B
            const int vr = c * 16 + (lane >> 2);           // 0..127
            const u32 vcol = (((u32)((lane & 3) * 16)) ^ ((u32)(vr & 3) << 4)) >> 1;
            gload16(Vth + (size_t)vr * 2048 + kb + vcol,
                    lV + bb * 4096 + c * 512);
        }
    };

    stage(0, t_lo);
    __syncthreads();
    int buf = 0;

    for (int t = t_lo; t < t_hi; ++t) {
        const int kb = t * 32;
        if (t + 1 < t_hi) stage(buf ^ 1, t + 1);

        if (kb <= qw + 31) {
            const char* lKb = (const char*)(lK + buf * 4096);
            const char* lVb = (const char*)(lV + buf * 4096);
            const bool diag = (kb == qw);

            // K frags from LDS (swizzled rows of 256B)
            bf16x8 kf[8];
            const u32 ksw = ((u32)ql & 7) << 4;
#pragma unroll
            for (int ch = 0; ch < 8; ++ch)
                kf[ch] = *(const bf16x8*)(lKb + ql * 256 + (((u32)(ch * 32 + g * 16)) ^ ksw));

            f32x16 s_;
#pragma unroll
            for (int r = 0; r < 16; ++r) s_[r] = 0.f;
            __builtin_amdgcn_s_setprio(1);
#pragma unroll
            for (int ch = 0; ch < 8; ++ch)
                s_ = __builtin_amdgcn_mfma_f32_32x32x16_bf16(kf[ch], qf[ch], s_, 0, 0, 0);
            __builtin_amdgcn_s_setprio(0);

            // lane holds S^T[k'][q], k'(r) = (r&3)+8*(r>>2)+4*g
            float p[16];
            float tmax = -1e30f;
#pragma unroll
            for (int r = 0; r < 16; ++r) {
                int crow = (r & 3) + 8 * (r >> 2) + 4 * g;
                float v = s_[r];
                if (diag && (crow > ql)) v = -1e30f;   // causal mask
                p[r] = v;
                tmax = fmaxf(tmax, v);
            }
            // T13 defer-max: __all spans both halves -> no per-tile cross max
            if (!__all(tmax <= m_run + 8.0f)) {
                float jmax  = fmaxf(tmax, __shfl_xor(tmax, 32));
                float mnew  = fmaxf(m_run, jmax);
                float alpha = exp2f((m_run - mnew) * C2);
#pragma unroll
                for (int dt = 0; dt < 4; ++dt) acc[dt] = acc[dt] * alpha;
                l_run *= alpha;
                m_run = mnew;
            }
            float ssum = 0.f;
#pragma unroll
            for (int r = 0; r < 16; ++r) {
                float e = exp2f((p[r] - m_run) * C2);
                p[r] = e;
                ssum += e;
            }
            l_run += ssum;              // per-lane partial; merged after loop

            // P^T -> MFMA B-operand frags via one cross-half exchange
            u32 wb[8], sw[8];
#pragma unroll
            for (int j = 0; j < 8; ++j) wb[j] = pack_bf2(p[2 * j], p[2 * j + 1]);
#pragma unroll
            for (int j = 0; j < 8; ++j) sw[j] = __shfl_xor(wb[j], 32);
            Frag4 pf0, pf1;
#pragma unroll
            for (int u = 0; u < 4; ++u) {
                const bool own = (g == (u >> 1));
                pf0.u[u] = own ? wb[2 * g + (u & 1)]     : sw[2 * g + (u & 1)];
                pf1.u[u] = own ? wb[4 + 2 * g + (u & 1)] : sw[4 + 2 * g + (u & 1)];
            }

            // O^T += V^T * P^T ; V rows of 64B, swizzle (row&3)<<4
            __builtin_amdgcn_s_setprio(1);
#pragma unroll
            for (int dt = 0; dt < 4; ++dt) {
                const u32 vrow = (u32)(dt * 32 + ql);
                const u32 vsw = (vrow & 3) << 4;
                bf16x8 v0 = *(const bf16x8*)(lVb + vrow * 64 + (((u32)(g * 16)) ^ vsw));
                bf16x8 v1 = *(const bf16x8*)(lVb + vrow * 64 + (((u32)(32 + g * 16)) ^ vsw));
                acc[dt] = __builtin_amdgcn_mfma_f32_32x32x16_bf16(v0, pf0.v, acc[dt], 0, 0, 0);
                acc[dt] = __builtin_amdgcn_mfma_f32_32x32x16_bf16(v1, pf1.v, acc[dt], 0, 0, 0);
            }
            __builtin_amdgcn_s_setprio(0);
        }
        __syncthreads();
        buf ^= 1;
    }

    l_run += __shfl_xor(l_run, 32);     // merge half partials (before stores)

    if (ck == 2) {
        const float inv_l = 1.0f / l_run;
        u16* orow = obuf + (rowbase + q) * 2048 + h * 128;
#pragma unroll
        for (int dt = 0; dt < 4; ++dt) {
#pragma unroll
            for (int rr = 0; rr < 4; ++rr) {
                int d0 = dt * 32 + rr * 8 + g * 4;
                int r0 = rr * 4;
                u32 w0 = pack_bf2(acc[dt][r0] * inv_l,     acc[dt][r0 + 1] * inv_l);
                u32 w1 = pack_bf2(acc[dt][r0 + 2] * inv_l, acc[dt][r0 + 3] * inv_l);
                *(u32*)(orow + d0)     = w0;
                *(u32*)(orow + d0 + 2) = w1;
            }
        }
    } else {
        const int slot = (((bh << 3) | (qt - 8)) << 1) + ck;
        const int qloc = w * 32 + ql;
        float* po = pout + (size_t)slot * 16384 + (size_t)qloc * 128;
#pragma unroll
        for (int dt = 0; dt < 4; ++dt) {
#pragma unroll
            for (int rr = 0; rr < 4; ++rr) {
                int d0 = dt * 32 + rr * 8 + g * 4;
                int r0 = rr * 4;
                float4 v4 = make_float4(acc[dt][r0], acc[dt][r0 + 1],
                                        acc[dt][r0 + 2], acc[dt][r0 + 3]);
                *(float4*)(po + d0) = v4;
            }
        }
        if (g == 0) {
            float2* pm = (float2*)pml + slot * 128 + qloc;
            *pm = make_float2(m_run, l_run);
        }
    }
}

// ---------------- merge the two KV-chunk partials (qt >= 8) -----------------
__global__ __launch_bounds__(256) void attn_merge(
    const float* __restrict__ pout, const float* __restrict__ pml,
    u16* __restrict__ obuf)
{
    const int bid = blockIdx.x;          // 256 = bh(32) x qto(8)
    const int bh = bid >> 3, qto = bid & 7;
    const int b = bh >> 4, h = bh & 15;
    const int tid = threadIdx.x;
    const int qloc = tid >> 1, half = (tid & 1) * 64;
    const int base = ((bh << 3) | qto) << 1;
    const float C2 = 0.08838834764831845f * 1.44269504088896341f;

    const float2 ml0 = ((const float2*)pml)[(base + 0) * 128 + qloc];
    const float2 ml1 = ((const float2*)pml)[(base + 1) * 128 + qloc];
    const float ms = fmaxf(ml0.x, ml1.x);
    const float w0 = exp2f((ml0.x - ms) * C2);
    const float w1 = exp2f((ml1.x - ms) * C2);
    const float inv = 1.0f / (ml0.y * w0 + ml1.y * w1);

    const float* p0 = pout + (size_t)(base + 0) * 16384 + (size_t)qloc * 128 + half;
    const float* p1 = pout + (size_t)(base + 1) * 16384 + (size_t)qloc * 128 + half;
    const int qrow = (8 + qto) * 128 + qloc;
    u16* orow = obuf + ((size_t)b * 2048 + qrow) * 2048 + h * 128 + half;
#pragma unroll
    for (int j = 0; j < 64; j += 4) {
        float4 a = *(const float4*)(p0 + j);
        float4 c = *(const float4*)(p1 + j);
        float o0 = (a.x * w0 + c.x * w1) * inv;
        float o1 = (a.y * w0 + c.y * w1) * inv;
        float o2 = (a.z * w0 + c.z * w1) * inv;
        float o3 = (a.w * w0 + c.w * w1) * inv;
        *(u32*)(orow + j)     = pack_bf2(o0, o1);
        *(u32*)(orow + j + 2) = pack_bf2(o2, o3);
    }
}

extern "C" void kernel_launch(void* const* d_in, const int* in_sizes, int n_in,
                              void* d_out, int out_size, void* d_ws, size_t ws_size,
                              hipStream_t stream) {
    (void)in_sizes; (void)n_in; (void)out_size; (void)ws_size;
    const float* x    = (const float*)d_in[0];
    const float* Wqkv = (const float*)d_in[1];
    const float* bqkv = (const float*)d_in[2];
    const float* Wout = (const float*)d_in[3];
    const float* bout = (const float*)d_in[4];

    char* ws = (char*)d_ws;
    u16* xb  = (u16*)ws;                        // [4096,2048] bf16, 16 MB
    u16* wqb = (u16*)(ws + (size_t)16777216);   // [6144,2048] bf16, 24 MB
    u16* qkv = (u16*)(ws + (size_t)41943040);   // [4096,6144] bf16, 48 MB
    u16* ob  = xb;   // attention out reuses xb (x dead after GEMM1)
    u16* vtb = wqb;  // V^T [32,128,2048] bf16 16 MB reuses wqb
    u16* wob = wqb;  // W_out bf16 reuses wqb again (vtb dead after attn)
    float* pml = (float*)(ws + (size_t)33554432);  // 512KB in wqb tail hole
    float* pO  = (float*)d_out;  // 32 MB f32 partials: d_out is free scratch
                                 // until gemm2 overwrites it

    cvt_f32_bf16<<<2048, 256, 0, stream>>>(x, xb, 8388608L / 8);
    cvt_f32_bf16<<<2048, 256, 0, stream>>>(Wqkv, wqb, 12582912L / 8);
    gemm_nt<1><<<1536, 256, 0, stream>>>(xb, wqb, bqkv, qkv, 2048, 6144, 5);
    transpose_v<<<2048, 256, 0, stream>>>(qkv, vtb);
    attn_fwd<<<768, 256, 0, stream>>>(qkv, vtb, ob, pO, pml);
    attn_merge<<<256, 256, 0, stream>>>(pO, pml, ob);
    cvt_f32_bf16<<<2048, 256, 0, stream>>>(Wout, wob, 4194304L / 8);
    gemm_nt<0><<<512, 256, 0, stream>>>(ob, wob, bout, d_out, 2048, 2048, 5);
}

// Round 10
// 356.997 us; speedup vs baseline: 1.3105x; 1.3105x over previous
//
#include <hip/hip_runtime.h>
#include <stdint.h>

typedef short bf16x8 __attribute__((ext_vector_type(8)));
typedef float f32x4 __attribute__((ext_vector_type(4)));
typedef float f32x16 __attribute__((ext_vector_type(16)));
typedef unsigned short u16;
typedef unsigned int u32;

__device__ __forceinline__ u16 f2bf(float f) {
    u32 x = __float_as_uint(f);
    x += 0x7fffu + ((x >> 16) & 1u);
    return (u16)(x >> 16);
}
__device__ __forceinline__ u32 pack_bf2(float a, float b) {
    return (u32)f2bf(a) | ((u32)f2bf(b) << 16);
}

union Frag4 { u32 u[4]; bf16x8 v; };

// async global->LDS, 16B per lane; LDS dest is wave-uniform base + lane*16
__device__ __forceinline__ void gload16(const u16* g, u16* l) {
    __builtin_amdgcn_global_load_lds(
        (__attribute__((address_space(1))) void*)g,
        (__attribute__((address_space(3))) void*)l,
        16, 0, 0);
}

// ---------------- f32 -> bf16 cast, 8 elems/thread (G13: vectorized) --------
__global__ void cvt_f32_bf16(const float* __restrict__ in, u16* __restrict__ out, long n8) {
    long stride = (long)gridDim.x * blockDim.x;
    for (long i = (long)blockIdx.x * blockDim.x + threadIdx.x; i < n8; i += stride) {
        const float4* p = (const float4*)(in + i * 8);
        float4 a = p[0], b = p[1];
        uint4 o;
        o.x = pack_bf2(a.x, a.y);
        o.y = pack_bf2(a.z, a.w);
        o.z = pack_bf2(b.x, b.y);
        o.w = pack_bf2(b.z, b.w);
        ((uint4*)out)[i] = o;
    }
}

// ---------------- bf16 NT GEMM: out = A * B^T + bias ------------------------
// 128x128 tile, BK=64, 4 waves, dbuf LDS, T4 counted-vmcnt pipeline
// (stage t+2 after compute t, vmcnt(8) mid-loop). Validated rounds 7-9.
template<int OBF>
__global__ __launch_bounds__(256, 2) void gemm_nt(
    const u16* __restrict__ A, const u16* __restrict__ B,
    const float* __restrict__ bias, void* __restrict__ out,
    int K, int ldo, int gxsh)
{
    __shared__ __align__(16) u16 lA[2 * 128 * 64];
    __shared__ __align__(16) u16 lB[2 * 128 * 64];
    const int tid  = threadIdx.x;
    const int lane = tid & 63;
    const int w    = tid >> 6;
    const int wm = (w >> 1) * 64, wn = (w & 1) * 64;

    const int nwg = gridDim.x;
    const int bid = blockIdx.x;
    const int swz = (bid & 7) * (nwg >> 3) + (bid >> 3);
    const int bm = (swz & ((1 << gxsh) - 1)) * 128;
    const int bn = (swz >> gxsh) * 128;

    const int lr = lane >> 3;
    const u32 sb = (u32)((lane & 7) * 16);
    const int NT = K >> 6;

    auto stage = [&](int bb, int k0) {
#pragma unroll
        for (int i = 0; i < 4; ++i) {
            const int c = w * 4 + i;
            const int row = c * 8 + lr;
            const u32 col = (sb ^ ((u32)(row & 7) << 4)) >> 1;
            gload16(A + (size_t)(bm + row) * K + k0 + col, lA + bb * 8192 + c * 512);
            gload16(B + (size_t)(bn + row) * K + k0 + col, lB + bb * 8192 + c * 512);
        }
    };

    f32x4 acc[4][4];
#pragma unroll
    for (int i = 0; i < 4; ++i)
#pragma unroll
        for (int j = 0; j < 4; ++j)
#pragma unroll
            for (int r = 0; r < 4; ++r) acc[i][j][r] = 0.f;

    stage(0, 0);
    stage(1, 64);
    asm volatile("s_waitcnt vmcnt(8)" ::: "memory");
    __builtin_amdgcn_sched_barrier(0);
    __builtin_amdgcn_s_barrier();
    __builtin_amdgcn_sched_barrier(0);

    for (int t = 0; t < NT; ++t) {
        const int cur = t & 1;
        const char* pA = (const char*)(lA + cur * 8192);
        const char* pB = (const char*)(lB + cur * 8192);
#pragma unroll
        for (int kk = 0; kk < 2; ++kk) {
            bf16x8 af[4], bfr[4];
#pragma unroll
            for (int f = 0; f < 4; ++f) {
                const int m = wm + f * 16 + (lane & 15);
                const u32 byt = (u32)(kk * 64 + (lane >> 4) * 16) ^ ((u32)(m & 7) << 4);
                af[f]  = *(const bf16x8*)(pA + m * 128 + byt);
                const int n = wn + f * 16 + (lane & 15);
                const u32 bytb = (u32)(kk * 64 + (lane >> 4) * 16) ^ ((u32)(n & 7) << 4);
                bfr[f] = *(const bf16x8*)(pB + n * 128 + bytb);
            }
            __builtin_amdgcn_s_setprio(1);
#pragma unroll
            for (int i = 0; i < 4; ++i)
#pragma unroll
                for (int j = 0; j < 4; ++j)
                    acc[i][j] = __builtin_amdgcn_mfma_f32_16x16x32_bf16(af[i], bfr[j], acc[i][j], 0, 0, 0);
            __builtin_amdgcn_s_setprio(0);
        }
        __builtin_amdgcn_sched_barrier(0);
        __builtin_amdgcn_s_barrier();
        __builtin_amdgcn_sched_barrier(0);
        if (t + 2 < NT) {
            stage(cur, (t + 2) * 64);
            asm volatile("s_waitcnt vmcnt(8)" ::: "memory");
        } else {
            asm volatile("s_waitcnt vmcnt(0)" ::: "memory");
        }
        __builtin_amdgcn_sched_barrier(0);
        __builtin_amdgcn_s_barrier();
        __builtin_amdgcn_sched_barrier(0);
    }

#pragma unroll
    for (int i = 0; i < 4; ++i) {
        int m0 = bm + wm + i * 16 + ((lane >> 4) << 2);
#pragma unroll
        for (int j = 0; j < 4; ++j) {
            int n = bn + wn + j * 16 + (lane & 15);
            float bv = bias[n];
#pragma unroll
            for (int r = 0; r < 4; ++r) {
                float v = acc[i][j][r] + bv;
                if constexpr (OBF != 0)
                    ((u16*)out)[(size_t)(m0 + r) * ldo + n] = f2bf(v);
                else
                    ((float*)out)[(size_t)(m0 + r) * ldo + n] = v;
            }
        }
    }
}

// ---------------- V transpose: vt[b,h,d,t] <- qkv[b*2048+t][4096+h*128+d] ---
__global__ __launch_bounds__(256) void transpose_v(
    const u16* __restrict__ qkv, u16* __restrict__ vt)
{
    __shared__ u16 lt[64 * 64];
    const int tid = threadIdx.x;
    const int bid = blockIdx.x;
    const int tt    = bid & 31;
    const int dtile = (bid >> 5) & 1;
    const int h     = (bid >> 6) & 15;
    const int b     = bid >> 10;
    const u16* src = qkv + ((size_t)b * 2048 + tt * 64) * 6144 + 4096 + h * 128 + dtile * 64;

    const int r = tid >> 2, ce = (tid & 3) * 16;
    uint4 a0 = *(const uint4*)(src + (size_t)r * 6144 + ce);
    uint4 a1 = *(const uint4*)(src + (size_t)r * 6144 + ce + 8);
    const u32 swz = (u32)((r & 7) << 4);
    *(uint4*)((char*)lt + r * 128 + (((u32)(ce * 2)) ^ swz)) = a0;
    *(uint4*)((char*)lt + r * 128 + (((u32)(ce * 2 + 16)) ^ swz)) = a1;
    __syncthreads();

    const int d = tid >> 2;
    u16* dst = vt + ((size_t)(b * 16 + h) * 128 + dtile * 64 + d) * 2048 + tt * 64;
#pragma unroll
    for (int it = 0; it < 2; ++it) {
        const int t0 = (tid & 3) * 8 + it * 32;
        union { u16 hh[8]; uint4 q4; } u;
#pragma unroll
        for (int uu = 0; uu < 8; ++uu) {
            int trow = t0 + uu;
            u32 byt = (u32)(trow * 128) + (((u32)(d * 2)) ^ ((u32)((trow & 7) << 4)));
            u.hh[uu] = *(const u16*)((const char*)lt + byt);
        }
        *(uint4*)(dst + t0) = u.q4;
    }
}

// ---------------- causal flash attention (round-8 structure + chain-trim) ---
// 768 blocks (KV-split). KVBLK=64 double-buffered (64KB LDS), 4 waves x 32 q.
// Per-32-kv subtile inner loop (validated round 4/7/8). Chain-trim (validated
// numerically in round 9): no per-subtile cross-half shfl — defer check rides
// __all (spans both halves); l_run is a per-lane half-partial merged once
// after the loop. Only the P^T-exchange shfl round remains per subtile.
__constant__ unsigned char QT_TAB[24] = {15,15,7,14,14,13,13,6,12,12,11,11,5,10,10,9,9,4,8,8,3,2,1,0};
__constant__ unsigned char CK_TAB[24] = {0,1,2,0,1,0,1,2,0,1,0,1,2,0,1,0,1,2,0,1,2,2,2,2};

__global__ __launch_bounds__(256) void attn_fwd(
    const u16* __restrict__ qkv, const u16* __restrict__ vt,
    u16* __restrict__ obuf, float* __restrict__ pout, float* __restrict__ pml)
{
    __shared__ __align__(16) u16 lK[2 * 64 * 128];
    __shared__ __align__(16) u16 lV[2 * 128 * 64];
    const int tid  = threadIdx.x;
    const int lane = tid & 63;
    const int w    = tid >> 6;
    const int g    = lane >> 5;
    const int ql   = lane & 31;

    const int bid  = blockIdx.x;
    const int item = bid >> 5;
    const int bh   = bid & 31;
    const int qt   = QT_TAB[item];
    const int ck   = CK_TAB[item];
    const int b = bh >> 4, h = bh & 15;
    const size_t rowbase = (size_t)b * 2048;
    const int qb = qt * 128;
    const int qw = qb + w * 32;
    const int q  = qw + ql;
    const int t_lo = (ck == 1) ? (qt + 1) : 0;
    const int t_hi = (ck == 0) ? (qt + 1) : (2 * qt + 2);

    const u16* Khead = qkv + rowbase * 6144 + 2048 + h * 128;  // ld 6144
    const u16* Vth   = vt + (size_t)bh * 128 * 2048;           // Vt[d][t]

    bf16x8 qf[8];
    {
        const u16* qrow = qkv + (rowbase + q) * 6144 + h * 128;
#pragma unroll
        for (int ch = 0; ch < 8; ++ch)
            qf[ch] = *(const bf16x8*)(qrow + ch * 16 + g * 8);
    }

    f32x16 acc[4];
#pragma unroll
    for (int dt = 0; dt < 4; ++dt)
#pragma unroll
        for (int r = 0; r < 16; ++r) acc[dt][r] = 0.f;

    float m_run = -1e30f, l_run = 0.f;   // l_run: per-lane half-partial
    const float C2 = 0.08838834764831845f * 1.44269504088896341f; // scale*log2e

    auto stage = [&](int bb, int t) {
        const int kb = t * 64;
#pragma unroll
        for (int i = 0; i < 4; ++i) {
            const int c = w * 4 + i;
            const int kr = c * 4 + (lane >> 4);
            const u32 kcol = (((u32)((lane & 15) * 16)) ^ ((u32)(kr & 7) << 4)) >> 1;
            gload16(Khead + (size_t)(kb + kr) * 6144 + kcol,
                    lK + bb * 8192 + c * 512);
            const int vr = c * 8 + (lane >> 3);
            const u32 vcol = (((u32)((lane & 7) * 16)) ^ ((u32)(vr & 7) << 4)) >> 1;
            gload16(Vth + (size_t)vr * 2048 + kb + vcol,
                    lV + bb * 8192 + c * 512);
        }
    };

    stage(0, t_lo);
    __syncthreads();
    int buf = 0;

    for (int t = t_lo; t < t_hi; ++t) {
        const int kb = t * 64;
        if (t + 1 < t_hi) stage(buf ^ 1, t + 1);

        if (kb <= qw + 31) {
            const char* lKb = (const char*)(lK + buf * 8192);
            const char* lVb = (const char*)(lV + buf * 8192);
#pragma unroll
            for (int s = 0; s < 2; ++s) {
                const int kb2 = kb + s * 32;
                if (kb2 > qw + 31) break;          // wave-uniform
                const bool diag = (kb2 == qw);

                bf16x8 kf[8];
                const u32 krow = (u32)(s * 32 + ql);
                const u32 ksw = (krow & 7) << 4;
#pragma unroll
                for (int ch = 0; ch < 8; ++ch)
                    kf[ch] = *(const bf16x8*)(lKb + krow * 256 + (((u32)(ch * 32 + g * 16)) ^ ksw));

                f32x16 s_;
#pragma unroll
                for (int r = 0; r < 16; ++r) s_[r] = 0.f;
                __builtin_amdgcn_s_setprio(1);
#pragma unroll
                for (int ch = 0; ch < 8; ++ch)
                    s_ = __builtin_amdgcn_mfma_f32_32x32x16_bf16(kf[ch], qf[ch], s_, 0, 0, 0);
                __builtin_amdgcn_s_setprio(0);

                // lane holds S^T[k'][q], k'(r) = (r&3)+8*(r>>2)+4*g
                float p[16];
                float tmax = -1e30f;
#pragma unroll
                for (int r = 0; r < 16; ++r) {
                    int crow = (r & 3) + 8 * (r >> 2) + 4 * g;
                    float v = s_[r];
                    if (diag && (crow > ql)) v = -1e30f;   // causal mask
                    p[r] = v;
                    tmax = fmaxf(tmax, v);
                }
                // T13 defer-max: __all spans both halves -> no cross-half max
                if (!__all(tmax <= m_run + 8.0f)) {
                    float jmax  = fmaxf(tmax, __shfl_xor(tmax, 32));
                    float mnew  = fmaxf(m_run, jmax);
                    float alpha = exp2f((m_run - mnew) * C2);
#pragma unroll
                    for (int dt = 0; dt < 4; ++dt) acc[dt] = acc[dt] * alpha;
                    l_run *= alpha;
                    m_run = mnew;
                }
                float ssum = 0.f;
#pragma unroll
                for (int r = 0; r < 16; ++r) {
                    float e = exp2f((p[r] - m_run) * C2);
                    p[r] = e;
                    ssum += e;
                }
                l_run += ssum;          // per-lane partial; merged after loop

                u32 wb[8], sw[8];
#pragma unroll
                for (int j = 0; j < 8; ++j) wb[j] = pack_bf2(p[2 * j], p[2 * j + 1]);
#pragma unroll
                for (int j = 0; j < 8; ++j) sw[j] = __shfl_xor(wb[j], 32);
                Frag4 pf0, pf1;
#pragma unroll
                for (int u = 0; u < 4; ++u) {
                    const bool own = (g == (u >> 1));
                    pf0.u[u] = own ? wb[2 * g + (u & 1)]     : sw[2 * g + (u & 1)];
                    pf1.u[u] = own ? wb[4 + 2 * g + (u & 1)] : sw[4 + 2 * g + (u & 1)];
                }

                __builtin_amdgcn_s_setprio(1);
#pragma unroll
                for (int dt = 0; dt < 4; ++dt) {
                    const u32 vrow = (u32)(dt * 32 + ql);
                    const u32 vsw = (vrow & 7) << 4;
                    bf16x8 v0 = *(const bf16x8*)(lVb + vrow * 128 + (((u32)(s * 64 + g * 16)) ^ vsw));
                    bf16x8 v1 = *(const bf16x8*)(lVb + vrow * 128 + (((u32)(s * 64 + 32 + g * 16)) ^ vsw));
                    acc[dt] = __builtin_amdgcn_mfma_f32_32x32x16_bf16(v0, pf0.v, acc[dt], 0, 0, 0);
                    acc[dt] = __builtin_amdgcn_mfma_f32_32x32x16_bf16(v1, pf1.v, acc[dt], 0, 0, 0);
                }
                __builtin_amdgcn_s_setprio(0);
            }
        }
        __syncthreads();
        buf ^= 1;
    }

    l_run += __shfl_xor(l_run, 32);     // merge half partials (before stores)

    if (ck == 2) {
        const float inv_l = 1.0f / l_run;
        u16* orow = obuf + (rowbase + q) * 2048 + h * 128;
#pragma unroll
        for (int dt = 0; dt < 4; ++dt) {
#pragma unroll
            for (int rr = 0; rr < 4; ++rr) {
                int d0 = dt * 32 + rr * 8 + g * 4;
                int r0 = rr * 4;
                u32 w0 = pack_bf2(acc[dt][r0] * inv_l,     acc[dt][r0 + 1] * inv_l);
                u32 w1 = pack_bf2(acc[dt][r0 + 2] * inv_l, acc[dt][r0 + 3] * inv_l);
                *(u32*)(orow + d0)     = w0;
                *(u32*)(orow + d0 + 2) = w1;
            }
        }
    } else {
        const int slot = (((bh << 3) | (qt - 8)) << 1) + ck;
        const int qloc = w * 32 + ql;
        float* po = pout + (size_t)slot * 16384 + (size_t)qloc * 128;
#pragma unroll
        for (int dt = 0; dt < 4; ++dt) {
#pragma unroll
            for (int rr = 0; rr < 4; ++rr) {
                int d0 = dt * 32 + rr * 8 + g * 4;
                int r0 = rr * 4;
                float4 v4 = make_float4(acc[dt][r0], acc[dt][r0 + 1],
                                        acc[dt][r0 + 2], acc[dt][r0 + 3]);
                *(float4*)(po + d0) = v4;
            }
        }
        if (g == 0) {
            float2* pm = (float2*)pml + slot * 128 + qloc;
            *pm = make_float2(m_run, l_run);
        }
    }
}

// ---------------- merge the two KV-chunk partials (qt >= 8) -----------------
__global__ __launch_bounds__(256) void attn_merge(
    const float* __restrict__ pout, const float* __restrict__ pml,
    u16* __restrict__ obuf)
{
    const int bid = blockIdx.x;          // 256 = bh(32) x qto(8)
    const int bh = bid >> 3, qto = bid & 7;
    const int b = bh >> 4, h = bh & 15;
    const int tid = threadIdx.x;
    const int qloc = tid >> 1, half = (tid & 1) * 64;
    const int base = ((bh << 3) | qto) << 1;
    const float C2 = 0.08838834764831845f * 1.44269504088896341f;

    const float2 ml0 = ((const float2*)pml)[(base + 0) * 128 + qloc];
    const float2 ml1 = ((const float2*)pml)[(base + 1) * 128 + qloc];
    const float ms = fmaxf(ml0.x, ml1.x);
    const float w0 = exp2f((ml0.x - ms) * C2);
    const float w1 = exp2f((ml1.x - ms) * C2);
    const float inv = 1.0f / (ml0.y * w0 + ml1.y * w1);

    const float* p0 = pout + (size_t)(base + 0) * 16384 + (size_t)qloc * 128 + half;
    const float* p1 = pout + (size_t)(base + 1) * 16384 + (size_t)qloc * 128 + half;
    const int qrow = (8 + qto) * 128 + qloc;
    u16* orow = obuf + ((size_t)b * 2048 + qrow) * 2048 + h * 128 + half;
#pragma unroll
    for (int j = 0; j < 64; j += 4) {
        float4 a = *(const float4*)(p0 + j);
        float4 c = *(const float4*)(p1 + j);
        float o0 = (a.x * w0 + c.x * w1) * inv;
        float o1 = (a.y * w0 + c.y * w1) * inv;
        float o2 = (a.z * w0 + c.z * w1) * inv;
        float o3 = (a.w * w0 + c.w * w1) * inv;
        *(u32*)(orow + j)     = pack_bf2(o0, o1);
        *(u32*)(orow + j + 2) = pack_bf2(o2, o3);
    }
}

extern "C" void kernel_launch(void* const* d_in, const int* in_sizes, int n_in,
                              void* d_out, int out_size, void* d_ws, size_t ws_size,
                              hipStream_t stream) {
    (void)in_sizes; (void)n_in; (void)out_size; (void)ws_size;
    const float* x    = (const float*)d_in[0];
    const float* Wqkv = (const float*)d_in[1];
    const float* bqkv = (const float*)d_in[2];
    const float* Wout = (const float*)d_in[3];
    const float* bout = (const float*)d_in[4];

    char* ws = (char*)d_ws;
    u16* xb  = (u16*)ws;                        // [4096,2048] bf16, 16 MB
    u16* wqb = (u16*)(ws + (size_t)16777216);   // [6144,2048] bf16, 24 MB
    u16* qkv = (u16*)(ws + (size_t)41943040);   // [4096,6144] bf16, 48 MB
    u16* ob  = xb;   // attention out reuses xb (x dead after GEMM1)
    u16* vtb = wqb;  // V^T [32,128,2048] bf16 16 MB reuses wqb
    u16* wob = wqb;  // W_out bf16 reuses wqb again (vtb dead after attn)
    float* pml = (float*)(ws + (size_t)33554432);  // 512KB in wqb tail hole
    float* pO  = (float*)d_out;  // 32 MB f32 partials: d_out is free scratch
                                 // until gemm2 overwrites it

    cvt_f32_bf16<<<2048, 256, 0, stream>>>(x, xb, 8388608L / 8);
    cvt_f32_bf16<<<2048, 256, 0, stream>>>(Wqkv, wqb, 12582912L / 8);
    gemm_nt<1><<<1536, 256, 0, stream>>>(xb, wqb, bqkv, qkv, 2048, 6144, 5);
    transpose_v<<<2048, 256, 0, stream>>>(qkv, vtb);
    attn_fwd<<<768, 256, 0, stream>>>(qkv, vtb, ob, pO, pml);
    attn_merge<<<256, 256, 0, stream>>>(pO, pml, ob);
    cvt_f32_bf16<<<2048, 256, 0, stream>>>(Wout, wob, 4194304L / 8);
    gemm_nt<0><<<512, 256, 0, stream>>>(ob, wob, bout, d_out, 2048, 2048, 5);
}

// Round 11
// 312.860 us; speedup vs baseline: 1.4953x; 1.1411x over previous
//
#include <hip/hip_runtime.h>
#include <stdint.h>

typedef short bf16x8 __attribute__((ext_vector_type(8)));
typedef float f32x4 __attribute__((ext_vector_type(4)));
typedef float f32x16 __attribute__((ext_vector_type(16)));
typedef unsigned short u16;
typedef unsigned int u32;

__device__ __forceinline__ u16 f2bf(float f) {
    u32 x = __float_as_uint(f);
    x += 0x7fffu + ((x >> 16) & 1u);
    return (u16)(x >> 16);
}
__device__ __forceinline__ u32 pack_bf2(float a, float b) {
    return (u32)f2bf(a) | ((u32)f2bf(b) << 16);
}

union Frag4 { u32 u[4]; bf16x8 v; };

// async global->LDS, 16B per lane; LDS dest is wave-uniform base + lane*16
__device__ __forceinline__ void gload16(const u16* g, u16* l) {
    __builtin_amdgcn_global_load_lds(
        (__attribute__((address_space(1))) void*)g,
        (__attribute__((address_space(3))) void*)l,
        16, 0, 0);
}

// ---------------- f32 -> bf16 cast, 8 elems/thread (G13: vectorized) --------
__global__ void cvt_f32_bf16(const float* __restrict__ in, u16* __restrict__ out, long n8) {
    long stride = (long)gridDim.x * blockDim.x;
    for (long i = (long)blockIdx.x * blockDim.x + threadIdx.x; i < n8; i += stride) {
        const float4* p = (const float4*)(in + i * 8);
        float4 a = p[0], b = p[1];
        uint4 o;
        o.x = pack_bf2(a.x, a.y);
        o.y = pack_bf2(a.z, a.w);
        o.z = pack_bf2(b.x, b.y);
        o.w = pack_bf2(b.z, b.w);
        ((uint4*)out)[i] = o;
    }
}

// ---------------- bf16 NT GEMM: out = A * B^T + bias ------------------------
// 128x128 tile, BK=64, 4 waves, dbuf LDS, T4 counted-vmcnt pipeline
// (stage t+2 after compute t, vmcnt(8) mid-loop). Validated rounds 7-10.
template<int OBF>
__global__ __launch_bounds__(256, 2) void gemm_nt(
    const u16* __restrict__ A, const u16* __restrict__ B,
    const float* __restrict__ bias, void* __restrict__ out,
    int K, int ldo, int gxsh)
{
    __shared__ __align__(16) u16 lA[2 * 128 * 64];
    __shared__ __align__(16) u16 lB[2 * 128 * 64];
    const int tid  = threadIdx.x;
    const int lane = tid & 63;
    const int w    = tid >> 6;
    const int wm = (w >> 1) * 64, wn = (w & 1) * 64;

    const int nwg = gridDim.x;
    const int bid = blockIdx.x;
    const int swz = (bid & 7) * (nwg >> 3) + (bid >> 3);
    const int bm = (swz & ((1 << gxsh) - 1)) * 128;
    const int bn = (swz >> gxsh) * 128;

    const int lr = lane >> 3;
    const u32 sb = (u32)((lane & 7) * 16);
    const int NT = K >> 6;

    auto stage = [&](int bb, int k0) {
#pragma unroll
        for (int i = 0; i < 4; ++i) {
            const int c = w * 4 + i;
            const int row = c * 8 + lr;
            const u32 col = (sb ^ ((u32)(row & 7) << 4)) >> 1;
            gload16(A + (size_t)(bm + row) * K + k0 + col, lA + bb * 8192 + c * 512);
            gload16(B + (size_t)(bn + row) * K + k0 + col, lB + bb * 8192 + c * 512);
        }
    };

    f32x4 acc[4][4];
#pragma unroll
    for (int i = 0; i < 4; ++i)
#pragma unroll
        for (int j = 0; j < 4; ++j)
#pragma unroll
            for (int r = 0; r < 4; ++r) acc[i][j][r] = 0.f;

    stage(0, 0);
    stage(1, 64);
    asm volatile("s_waitcnt vmcnt(8)" ::: "memory");
    __builtin_amdgcn_sched_barrier(0);
    __builtin_amdgcn_s_barrier();
    __builtin_amdgcn_sched_barrier(0);

    for (int t = 0; t < NT; ++t) {
        const int cur = t & 1;
        const char* pA = (const char*)(lA + cur * 8192);
        const char* pB = (const char*)(lB + cur * 8192);
#pragma unroll
        for (int kk = 0; kk < 2; ++kk) {
            bf16x8 af[4], bfr[4];
#pragma unroll
            for (int f = 0; f < 4; ++f) {
                const int m = wm + f * 16 + (lane & 15);
                const u32 byt = (u32)(kk * 64 + (lane >> 4) * 16) ^ ((u32)(m & 7) << 4);
                af[f]  = *(const bf16x8*)(pA + m * 128 + byt);
                const int n = wn + f * 16 + (lane & 15);
                const u32 bytb = (u32)(kk * 64 + (lane >> 4) * 16) ^ ((u32)(n & 7) << 4);
                bfr[f] = *(const bf16x8*)(pB + n * 128 + bytb);
            }
            __builtin_amdgcn_s_setprio(1);
#pragma unroll
            for (int i = 0; i < 4; ++i)
#pragma unroll
                for (int j = 0; j < 4; ++j)
                    acc[i][j] = __builtin_amdgcn_mfma_f32_16x16x32_bf16(af[i], bfr[j], acc[i][j], 0, 0, 0);
            __builtin_amdgcn_s_setprio(0);
        }
        __builtin_amdgcn_sched_barrier(0);
        __builtin_amdgcn_s_barrier();
        __builtin_amdgcn_sched_barrier(0);
        if (t + 2 < NT) {
            stage(cur, (t + 2) * 64);
            asm volatile("s_waitcnt vmcnt(8)" ::: "memory");
        } else {
            asm volatile("s_waitcnt vmcnt(0)" ::: "memory");
        }
        __builtin_amdgcn_sched_barrier(0);
        __builtin_amdgcn_s_barrier();
        __builtin_amdgcn_sched_barrier(0);
    }

#pragma unroll
    for (int i = 0; i < 4; ++i) {
        int m0 = bm + wm + i * 16 + ((lane >> 4) << 2);
#pragma unroll
        for (int j = 0; j < 4; ++j) {
            int n = bn + wn + j * 16 + (lane & 15);
            float bv = bias[n];
#pragma unroll
            for (int r = 0; r < 4; ++r) {
                float v = acc[i][j][r] + bv;
                if constexpr (OBF != 0)
                    ((u16*)out)[(size_t)(m0 + r) * ldo + n] = f2bf(v);
                else
                    ((float*)out)[(size_t)(m0 + r) * ldo + n] = v;
            }
        }
    }
}

// ---------------- V transpose: vt[b,h,d,t] <- qkv[b*2048+t][4096+h*128+d] ---
__global__ __launch_bounds__(256) void transpose_v(
    const u16* __restrict__ qkv, u16* __restrict__ vt)
{
    __shared__ u16 lt[64 * 64];
    const int tid = threadIdx.x;
    const int bid = blockIdx.x;
    const int tt    = bid & 31;
    const int dtile = (bid >> 5) & 1;
    const int h     = (bid >> 6) & 15;
    const int b     = bid >> 10;
    const u16* src = qkv + ((size_t)b * 2048 + tt * 64) * 6144 + 4096 + h * 128 + dtile * 64;

    const int r = tid >> 2, ce = (tid & 3) * 16;
    uint4 a0 = *(const uint4*)(src + (size_t)r * 6144 + ce);
    uint4 a1 = *(const uint4*)(src + (size_t)r * 6144 + ce + 8);
    const u32 swz = (u32)((r & 7) << 4);
    *(uint4*)((char*)lt + r * 128 + (((u32)(ce * 2)) ^ swz)) = a0;
    *(uint4*)((char*)lt + r * 128 + (((u32)(ce * 2 + 16)) ^ swz)) = a1;
    __syncthreads();

    const int d = tid >> 2;
    u16* dst = vt + ((size_t)(b * 16 + h) * 128 + dtile * 64 + d) * 2048 + tt * 64;
#pragma unroll
    for (int it = 0; it < 2; ++it) {
        const int t0 = (tid & 3) * 8 + it * 32;
        union { u16 hh[8]; uint4 q4; } u;
#pragma unroll
        for (int uu = 0; uu < 8; ++uu) {
            int trow = t0 + uu;
            u32 byt = (u32)(trow * 128) + (((u32)(d * 2)) ^ ((u32)((trow & 7) << 4)));
            u.hh[uu] = *(const u16*)((const char*)lt + byt);
        }
        *(uint4*)(dst + t0) = u.q4;
    }
}

// ---------------- causal flash attention -----------------------------------
// Round-8 inner loop (validated, natural ~140 VGPR) + KVBLK=32 dbuf staging
// (validated round 9) -> 32KB LDS. No min-waves bound: with VGPR<=170 and
// LDS 32KB the HW occupancy rules give 3 blocks/CU (12 waves/CU, +50% TLP
// over round 8's LDS-capped 2 blocks/CU).
__constant__ unsigned char QT_TAB[24] = {15,15,7,14,14,13,13,6,12,12,11,11,5,10,10,9,9,4,8,8,3,2,1,0};
__constant__ unsigned char CK_TAB[24] = {0,1,2,0,1,0,1,2,0,1,0,1,2,0,1,0,1,2,0,1,2,2,2,2};

__global__ __launch_bounds__(256) void attn_fwd(
    const u16* __restrict__ qkv, const u16* __restrict__ vt,
    u16* __restrict__ obuf, float* __restrict__ pout, float* __restrict__ pml)
{
    __shared__ __align__(16) u16 lK[2 * 32 * 128];   // [32 kv][128 d] per buf
    __shared__ __align__(16) u16 lV[2 * 128 * 32];   // [128 d][32 kv] per buf
    const int tid  = threadIdx.x;
    const int lane = tid & 63;
    const int w    = tid >> 6;
    const int g    = lane >> 5;
    const int ql   = lane & 31;

    const int bid  = blockIdx.x;
    const int item = bid >> 5;
    const int bh   = bid & 31;
    const int qt   = QT_TAB[item];
    const int ck   = CK_TAB[item];
    const int b = bh >> 4, h = bh & 15;
    const size_t rowbase = (size_t)b * 2048;
    const int qb = qt * 128;
    const int qw = qb + w * 32;
    const int q  = qw + ql;
    // KV tiles of 32; split boundary at tile 2qt+2 (kv = 64qt+64 <= qb)
    const int t_lo = (ck == 1) ? (2 * qt + 2) : 0;
    const int t_hi = (ck == 0) ? (2 * qt + 2) : (4 * qt + 4);

    const u16* Khead = qkv + rowbase * 6144 + 2048 + h * 128;  // ld 6144
    const u16* Vth   = vt + (size_t)bh * 128 * 2048;           // Vt[d][t]

    bf16x8 qf[8];
    {
        const u16* qrow = qkv + (rowbase + q) * 6144 + h * 128;
#pragma unroll
        for (int ch = 0; ch < 8; ++ch)
            qf[ch] = *(const bf16x8*)(qrow + ch * 16 + g * 8);
    }

    f32x16 acc[4];
#pragma unroll
    for (int dt = 0; dt < 4; ++dt)
#pragma unroll
        for (int r = 0; r < 16; ++r) acc[dt][r] = 0.f;

    float m_run = -1e30f, l_run = 0.f;
    const float C2 = 0.08838834764831845f * 1.44269504088896341f; // scale*log2e

    // stage 32-kv tile t into buffer bb: per wave 2 K chunks + 2 V chunks
    auto stage = [&](int bb, int t) {
        const int kb = t * 32;
#pragma unroll
        for (int i = 0; i < 2; ++i) {
            const int c = w * 2 + i;                       // 0..7
            // K chunk: 4 rows x 256B
            const int kr = c * 4 + (lane >> 4);            // 0..31
            const u32 kcol = (((u32)((lane & 15) * 16)) ^ ((u32)(kr & 7) << 4)) >> 1;
            gload16(Khead + (size_t)(kb + kr) * 6144 + kcol,
                    lK + bb * 4096 + c * 512);
            // V chunk: 16 rows x 64B
            const int vr = c * 16 + (lane >> 2);           // 0..127
            const u32 vcol = (((u32)((lane & 3) * 16)) ^ ((u32)(vr & 3) << 4)) >> 1;
            gload16(Vth + (size_t)vr * 2048 + kb + vcol,
                    lV + bb * 4096 + c * 512);
        }
    };

    stage(0, t_lo);
    __syncthreads();
    int buf = 0;

    for (int t = t_lo; t < t_hi; ++t) {
        const int kb = t * 32;
        if (t + 1 < t_hi) stage(buf ^ 1, t + 1);

        if (kb <= qw + 31) {
            const char* lKb = (const char*)(lK + buf * 4096);
            const char* lVb = (const char*)(lV + buf * 4096);
            const bool diag = (kb == qw);

            // K frags from LDS (swizzled rows of 256B)
            bf16x8 kf[8];
            const u32 ksw = ((u32)ql & 7) << 4;
#pragma unroll
            for (int ch = 0; ch < 8; ++ch)
                kf[ch] = *(const bf16x8*)(lKb + ql * 256 + (((u32)(ch * 32 + g * 16)) ^ ksw));

            f32x16 s_;
#pragma unroll
            for (int r = 0; r < 16; ++r) s_[r] = 0.f;
            __builtin_amdgcn_s_setprio(1);
#pragma unroll
            for (int ch = 0; ch < 8; ++ch)
                s_ = __builtin_amdgcn_mfma_f32_32x32x16_bf16(kf[ch], qf[ch], s_, 0, 0, 0);
            __builtin_amdgcn_s_setprio(0);

            // lane holds S^T[k'][q], k'(r) = (r&3)+8*(r>>2)+4*g
            float p[16];
            float tmax = -1e30f;
#pragma unroll
            for (int r = 0; r < 16; ++r) {
                int crow = (r & 3) + 8 * (r >> 2) + 4 * g;
                float v = s_[r];
                if (diag && (crow > ql)) v = -1e30f;   // causal mask
                p[r] = v;
                tmax = fmaxf(tmax, v);
            }
            tmax = fmaxf(tmax, __shfl_xor(tmax, 32));
            // T13 defer-max: skip O/l rescale while max grows < 8
            if (!__all(tmax <= m_run + 8.0f)) {
                float mnew  = fmaxf(m_run, tmax);
                float alpha = exp2f((m_run - mnew) * C2);
#pragma unroll
                for (int dt = 0; dt < 4; ++dt) acc[dt] = acc[dt] * alpha;
                l_run *= alpha;
                m_run = mnew;
            }
            float ssum = 0.f;
#pragma unroll
            for (int r = 0; r < 16; ++r) {
                float e = exp2f((p[r] - m_run) * C2);
                p[r] = e;
                ssum += e;
            }
            ssum += __shfl_xor(ssum, 32);
            l_run += ssum;

            // P^T -> MFMA B-operand frags via one cross-half exchange
            u32 wb[8], sw[8];
#pragma unroll
            for (int j = 0; j < 8; ++j) wb[j] = pack_bf2(p[2 * j], p[2 * j + 1]);
#pragma unroll
            for (int j = 0; j < 8; ++j) sw[j] = __shfl_xor(wb[j], 32);
            Frag4 pf0, pf1;
#pragma unroll
            for (int u = 0; u < 4; ++u) {
                const bool own = (g == (u >> 1));
                pf0.u[u] = own ? wb[2 * g + (u & 1)]     : sw[2 * g + (u & 1)];
                pf1.u[u] = own ? wb[4 + 2 * g + (u & 1)] : sw[4 + 2 * g + (u & 1)];
            }

            // O^T += V^T * P^T ; V rows of 64B, swizzle (row&3)<<4
            __builtin_amdgcn_s_setprio(1);
#pragma unroll
            for (int dt = 0; dt < 4; ++dt) {
                const u32 vrow = (u32)(dt * 32 + ql);
                const u32 vsw = (vrow & 3) << 4;
                bf16x8 v0 = *(const bf16x8*)(lVb + vrow * 64 + (((u32)(g * 16)) ^ vsw));
                bf16x8 v1 = *(const bf16x8*)(lVb + vrow * 64 + (((u32)(32 + g * 16)) ^ vsw));
                acc[dt] = __builtin_amdgcn_mfma_f32_32x32x16_bf16(v0, pf0.v, acc[dt], 0, 0, 0);
                acc[dt] = __builtin_amdgcn_mfma_f32_32x32x16_bf16(v1, pf1.v, acc[dt], 0, 0, 0);
            }
            __builtin_amdgcn_s_setprio(0);
        }
        __syncthreads();
        buf ^= 1;
    }

    if (ck == 2) {
        const float inv_l = 1.0f / l_run;
        u16* orow = obuf + (rowbase + q) * 2048 + h * 128;
#pragma unroll
        for (int dt = 0; dt < 4; ++dt) {
#pragma unroll
            for (int rr = 0; rr < 4; ++rr) {
                int d0 = dt * 32 + rr * 8 + g * 4;
                int r0 = rr * 4;
                u32 w0 = pack_bf2(acc[dt][r0] * inv_l,     acc[dt][r0 + 1] * inv_l);
                u32 w1 = pack_bf2(acc[dt][r0 + 2] * inv_l, acc[dt][r0 + 3] * inv_l);
                *(u32*)(orow + d0)     = w0;
                *(u32*)(orow + d0 + 2) = w1;
            }
        }
    } else {
        const int slot = (((bh << 3) | (qt - 8)) << 1) + ck;
        const int qloc = w * 32 + ql;
        float* po = pout + (size_t)slot * 16384 + (size_t)qloc * 128;
#pragma unroll
        for (int dt = 0; dt < 4; ++dt) {
#pragma unroll
            for (int rr = 0; rr < 4; ++rr) {
                int d0 = dt * 32 + rr * 8 + g * 4;
                int r0 = rr * 4;
                float4 v4 = make_float4(acc[dt][r0], acc[dt][r0 + 1],
                                        acc[dt][r0 + 2], acc[dt][r0 + 3]);
                *(float4*)(po + d0) = v4;
            }
        }
        if (g == 0) {
            float2* pm = (float2*)pml + slot * 128 + qloc;
            *pm = make_float2(m_run, l_run);
        }
    }
}

// ---------------- merge the two KV-chunk partials (qt >= 8) -----------------
__global__ __launch_bounds__(256) void attn_merge(
    const float* __restrict__ pout, const float* __restrict__ pml,
    u16* __restrict__ obuf)
{
    const int bid = blockIdx.x;          // 256 = bh(32) x qto(8)
    const int bh = bid >> 3, qto = bid & 7;
    const int b = bh >> 4, h = bh & 15;
    const int tid = threadIdx.x;
    const int qloc = tid >> 1, half = (tid & 1) * 64;
    const int base = ((bh << 3) | qto) << 1;
    const float C2 = 0.08838834764831845f * 1.44269504088896341f;

    const float2 ml0 = ((const float2*)pml)[(base + 0) * 128 + qloc];
    const float2 ml1 = ((const float2*)pml)[(base + 1) * 128 + qloc];
    const float ms = fmaxf(ml0.x, ml1.x);
    const float w0 = exp2f((ml0.x - ms) * C2);
    const float w1 = exp2f((ml1.x - ms) * C2);
    const float inv = 1.0f / (ml0.y * w0 + ml1.y * w1);

    const float* p0 = pout + (size_t)(base + 0) * 16384 + (size_t)qloc * 128 + half;
    const float* p1 = pout + (size_t)(base + 1) * 16384 + (size_t)qloc * 128 + half;
    const int qrow = (8 + qto) * 128 + qloc;
    u16* orow = obuf + ((size_t)b * 2048 + qrow) * 2048 + h * 128 + half;
#pragma unroll
    for (int j = 0; j < 64; j += 4) {
        float4 a = *(const float4*)(p0 + j);
        float4 c = *(const float4*)(p1 + j);
        float o0 = (a.x * w0 + c.x * w1) * inv;
        float o1 = (a.y * w0 + c.y * w1) * inv;
        float o2 = (a.z * w0 + c.z * w1) * inv;
        float o3 = (a.w * w0 + c.w * w1) * inv;
        *(u32*)(orow + j)     = pack_bf2(o0, o1);
        *(u32*)(orow + j + 2) = pack_bf2(o2, o3);
    }
}

extern "C" void kernel_launch(void* const* d_in, const int* in_sizes, int n_in,
                              void* d_out, int out_size, void* d_ws, size_t ws_size,
                              hipStream_t stream) {
    (void)in_sizes; (void)n_in; (void)out_size; (void)ws_size;
    const float* x    = (const float*)d_in[0];
    const float* Wqkv = (const float*)d_in[1];
    const float* bqkv = (const float*)d_in[2];
    const float* Wout = (const float*)d_in[3];
    const float* bout = (const float*)d_in[4];

    char* ws = (char*)d_ws;
    u16* xb  = (u16*)ws;                        // [4096,2048] bf16, 16 MB
    u16* wqb = (u16*)(ws + (size_t)16777216);   // [6144,2048] bf16, 24 MB
    u16* qkv = (u16*)(ws + (size_t)41943040);   // [4096,6144] bf16, 48 MB
    u16* ob  = xb;   // attention out reuses xb (x dead after GEMM1)
    u16* vtb = wqb;  // V^T [32,128,2048] bf16 16 MB reuses wqb
    u16* wob = wqb;  // W_out bf16 reuses wqb again (vtb dead after attn)
    float* pml = (float*)(ws + (size_t)33554432);  // 512KB in wqb tail hole
    float* pO  = (float*)d_out;  // 32 MB f32 partials: d_out is free scratch
                                 // until gemm2 overwrites it

    cvt_f32_bf16<<<2048, 256, 0, stream>>>(x, xb, 8388608L / 8);
    cvt_f32_bf16<<<2048, 256, 0, stream>>>(Wqkv, wqb, 12582912L / 8);
    gemm_nt<1><<<1536, 256, 0, stream>>>(xb, wqb, bqkv, qkv, 2048, 6144, 5);
    transpose_v<<<2048, 256, 0, stream>>>(qkv, vtb);
    attn_fwd<<<768, 256, 0, stream>>>(qkv, vtb, ob, pO, pml);
    attn_merge<<<256, 256, 0, stream>>>(pO, pml, ob);
    cvt_f32_bf16<<<2048, 256, 0, stream>>>(Wout, wob, 4194304L / 8);
    gemm_nt<0><<<512, 256, 0, stream>>>(ob, wob, bout, d_out, 2048, 2048, 5);
}

// Round 12
// 308.138 us; speedup vs baseline: 1.5183x; 1.0153x over previous
//
#include <hip/hip_runtime.h>
#include <stdint.h>

typedef short bf16x8 __attribute__((ext_vector_type(8)));
typedef float f32x4 __attribute__((ext_vector_type(4)));
typedef float f32x16 __attribute__((ext_vector_type(16)));
typedef unsigned short u16;
typedef unsigned int u32;

__device__ __forceinline__ u16 f2bf(float f) {
    u32 x = __float_as_uint(f);
    x += 0x7fffu + ((x >> 16) & 1u);
    return (u16)(x >> 16);
}
__device__ __forceinline__ u32 pack_bf2(float a, float b) {
    return (u32)f2bf(a) | ((u32)f2bf(b) << 16);
}
__device__ __forceinline__ float bf2f(u16 v) {
    return __uint_as_float(((u32)v) << 16);
}

union Frag4 { u32 u[4]; bf16x8 v; };

// async global->LDS, 16B per lane; LDS dest is wave-uniform base + lane*16
__device__ __forceinline__ void gload16(const u16* g, u16* l) {
    __builtin_amdgcn_global_load_lds(
        (__attribute__((address_space(1))) void*)g,
        (__attribute__((address_space(3))) void*)l,
        16, 0, 0);
}

// ---------------- f32 -> bf16 cast, 8 elems/thread (G13: vectorized) --------
__global__ void cvt_f32_bf16(const float* __restrict__ in, u16* __restrict__ out, long n8) {
    long stride = (long)gridDim.x * blockDim.x;
    for (long i = (long)blockIdx.x * blockDim.x + threadIdx.x; i < n8; i += stride) {
        const float4* p = (const float4*)(in + i * 8);
        float4 a = p[0], b = p[1];
        uint4 o;
        o.x = pack_bf2(a.x, a.y);
        o.y = pack_bf2(a.z, a.w);
        o.z = pack_bf2(b.x, b.y);
        o.w = pack_bf2(b.z, b.w);
        ((uint4*)out)[i] = o;
    }
}

// ---------------- bf16 NT GEMM: out = A * B^T + bias ------------------------
// 128x128 tile, BK=64, 4 waves, dbuf LDS, T4 counted-vmcnt pipeline
// (stage t+2 after compute t, vmcnt(8) mid-loop). Validated rounds 7-11.
template<int OBF>
__global__ __launch_bounds__(256, 2) void gemm_nt(
    const u16* __restrict__ A, const u16* __restrict__ B,
    const float* __restrict__ bias, void* __restrict__ out,
    int K, int ldo, int gxsh)
{
    __shared__ __align__(16) u16 lA[2 * 128 * 64];
    __shared__ __align__(16) u16 lB[2 * 128 * 64];
    const int tid  = threadIdx.x;
    const int lane = tid & 63;
    const int w    = tid >> 6;
    const int wm = (w >> 1) * 64, wn = (w & 1) * 64;

    const int nwg = gridDim.x;
    const int bid = blockIdx.x;
    const int swz = (bid & 7) * (nwg >> 3) + (bid >> 3);
    const int bm = (swz & ((1 << gxsh) - 1)) * 128;
    const int bn = (swz >> gxsh) * 128;

    const int lr = lane >> 3;
    const u32 sb = (u32)((lane & 7) * 16);
    const int NT = K >> 6;

    auto stage = [&](int bb, int k0) {
#pragma unroll
        for (int i = 0; i < 4; ++i) {
            const int c = w * 4 + i;
            const int row = c * 8 + lr;
            const u32 col = (sb ^ ((u32)(row & 7) << 4)) >> 1;
            gload16(A + (size_t)(bm + row) * K + k0 + col, lA + bb * 8192 + c * 512);
            gload16(B + (size_t)(bn + row) * K + k0 + col, lB + bb * 8192 + c * 512);
        }
    };

    f32x4 acc[4][4];
#pragma unroll
    for (int i = 0; i < 4; ++i)
#pragma unroll
        for (int j = 0; j < 4; ++j)
#pragma unroll
            for (int r = 0; r < 4; ++r) acc[i][j][r] = 0.f;

    stage(0, 0);
    stage(1, 64);
    asm volatile("s_waitcnt vmcnt(8)" ::: "memory");
    __builtin_amdgcn_sched_barrier(0);
    __builtin_amdgcn_s_barrier();
    __builtin_amdgcn_sched_barrier(0);

    for (int t = 0; t < NT; ++t) {
        const int cur = t & 1;
        const char* pA = (const char*)(lA + cur * 8192);
        const char* pB = (const char*)(lB + cur * 8192);
#pragma unroll
        for (int kk = 0; kk < 2; ++kk) {
            bf16x8 af[4], bfr[4];
#pragma unroll
            for (int f = 0; f < 4; ++f) {
                const int m = wm + f * 16 + (lane & 15);
                const u32 byt = (u32)(kk * 64 + (lane >> 4) * 16) ^ ((u32)(m & 7) << 4);
                af[f]  = *(const bf16x8*)(pA + m * 128 + byt);
                const int n = wn + f * 16 + (lane & 15);
                const u32 bytb = (u32)(kk * 64 + (lane >> 4) * 16) ^ ((u32)(n & 7) << 4);
                bfr[f] = *(const bf16x8*)(pB + n * 128 + bytb);
            }
            __builtin_amdgcn_s_setprio(1);
#pragma unroll
            for (int i = 0; i < 4; ++i)
#pragma unroll
                for (int j = 0; j < 4; ++j)
                    acc[i][j] = __builtin_amdgcn_mfma_f32_16x16x32_bf16(af[i], bfr[j], acc[i][j], 0, 0, 0);
            __builtin_amdgcn_s_setprio(0);
        }
        __builtin_amdgcn_sched_barrier(0);
        __builtin_amdgcn_s_barrier();
        __builtin_amdgcn_sched_barrier(0);
        if (t + 2 < NT) {
            stage(cur, (t + 2) * 64);
            asm volatile("s_waitcnt vmcnt(8)" ::: "memory");
        } else {
            asm volatile("s_waitcnt vmcnt(0)" ::: "memory");
        }
        __builtin_amdgcn_sched_barrier(0);
        __builtin_amdgcn_s_barrier();
        __builtin_amdgcn_sched_barrier(0);
    }

#pragma unroll
    for (int i = 0; i < 4; ++i) {
        int m0 = bm + wm + i * 16 + ((lane >> 4) << 2);
#pragma unroll
        for (int j = 0; j < 4; ++j) {
            int n = bn + wn + j * 16 + (lane & 15);
            float bv = bias[n];
#pragma unroll
            for (int r = 0; r < 4; ++r) {
                float v = acc[i][j][r] + bv;
                if constexpr (OBF != 0)
                    ((u16*)out)[(size_t)(m0 + r) * ldo + n] = f2bf(v);
                else
                    ((float*)out)[(size_t)(m0 + r) * ldo + n] = v;
            }
        }
    }
}

// ---------------- V transpose: vt[b,h,d,t] <- qkv[b*2048+t][4096+h*128+d] ---
__global__ __launch_bounds__(256) void transpose_v(
    const u16* __restrict__ qkv, u16* __restrict__ vt)
{
    __shared__ u16 lt[64 * 64];
    const int tid = threadIdx.x;
    const int bid = blockIdx.x;
    const int tt    = bid & 31;
    const int dtile = (bid >> 5) & 1;
    const int h     = (bid >> 6) & 15;
    const int b     = bid >> 10;
    const u16* src = qkv + ((size_t)b * 2048 + tt * 64) * 6144 + 4096 + h * 128 + dtile * 64;

    const int r = tid >> 2, ce = (tid & 3) * 16;
    uint4 a0 = *(const uint4*)(src + (size_t)r * 6144 + ce);
    uint4 a1 = *(const uint4*)(src + (size_t)r * 6144 + ce + 8);
    const u32 swz = (u32)((r & 7) << 4);
    *(uint4*)((char*)lt + r * 128 + (((u32)(ce * 2)) ^ swz)) = a0;
    *(uint4*)((char*)lt + r * 128 + (((u32)(ce * 2 + 16)) ^ swz)) = a1;
    __syncthreads();

    const int d = tid >> 2;
    u16* dst = vt + ((size_t)(b * 16 + h) * 128 + dtile * 64 + d) * 2048 + tt * 64;
#pragma unroll
    for (int it = 0; it < 2; ++it) {
        const int t0 = (tid & 3) * 8 + it * 32;
        union { u16 hh[8]; uint4 q4; } u;
#pragma unroll
        for (int uu = 0; uu < 8; ++uu) {
            int trow = t0 + uu;
            u32 byt = (u32)(trow * 128) + (((u32)(d * 2)) ^ ((u32)((trow & 7) << 4)));
            u.hh[uu] = *(const u16*)((const char*)lt + byt);
        }
        *(uint4*)(dst + t0) = u.q4;
    }
}

// ---------------- causal flash attention (uniform-chunk KV-split) -----------
// Round-11 validated inner loop (KVBLK=32 dbuf, 32KB LDS, 128 VGPR, 3
// blocks/CU). Work-balanced chunking: qt<=5 direct; qt 6-11 split x2,
// qt 12-15 split x3 -> 30 items/bh, 960 blocks, longest 24 tiles (was 32),
// LPT dispatch order. Split chunks write bf16 partials + (m,l); exact merge.
__constant__ unsigned char QT_TAB[30] = {11,11, 5,15,15,15,10,10,14,14,14, 9, 9, 4,13,13,13,12,12,12, 8, 8, 7, 7, 3, 6, 6, 2, 1, 0};
__constant__ unsigned char TLO_TAB[30]= { 0,24, 0, 0,22,43, 0,22, 0,20,40, 0,20, 0, 0,19,38, 0,18,36, 0,18, 0,16, 0, 0,14, 0, 0, 0};
__constant__ unsigned char THI_TAB[30]= {24,48,24,22,43,64,22,44,20,40,60,20,40,20,19,38,56,18,36,52,18,36,16,32,16,14,28,12, 8, 4};
__constant__ unsigned char SL_TAB[30] = {10,11,255,21,22,23, 8, 9,18,19,20, 6, 7,255,15,16,17,12,13,14, 4, 5, 2, 3,255, 0, 1,255,255,255};

__global__ __launch_bounds__(256) void attn_fwd(
    const u16* __restrict__ qkv, const u16* __restrict__ vt,
    u16* __restrict__ obuf, u16* __restrict__ pout, float* __restrict__ pml)
{
    __shared__ __align__(16) u16 lK[2 * 32 * 128];   // [32 kv][128 d] per buf
    __shared__ __align__(16) u16 lV[2 * 128 * 32];   // [128 d][32 kv] per buf
    const int tid  = threadIdx.x;
    const int lane = tid & 63;
    const int w    = tid >> 6;
    const int g    = lane >> 5;
    const int ql   = lane & 31;

    const int bid  = blockIdx.x;
    const int item = bid >> 5;
    const int bh   = bid & 31;
    const int qt   = QT_TAB[item];
    const int slot = SL_TAB[item];
    const int t_lo = TLO_TAB[item];
    const int t_hi = THI_TAB[item];
    const int b = bh >> 4, h = bh & 15;
    const size_t rowbase = (size_t)b * 2048;
    const int qb = qt * 128;
    const int qw = qb + w * 32;
    const int q  = qw + ql;

    const u16* Khead = qkv + rowbase * 6144 + 2048 + h * 128;  // ld 6144
    const u16* Vth   = vt + (size_t)bh * 128 * 2048;           // Vt[d][t]

    bf16x8 qf[8];
    {
        const u16* qrow = qkv + (rowbase + q) * 6144 + h * 128;
#pragma unroll
        for (int ch = 0; ch < 8; ++ch)
            qf[ch] = *(const bf16x8*)(qrow + ch * 16 + g * 8);
    }

    f32x16 acc[4];
#pragma unroll
    for (int dt = 0; dt < 4; ++dt)
#pragma unroll
        for (int r = 0; r < 16; ++r) acc[dt][r] = 0.f;

    float m_run = -1e30f, l_run = 0.f;
    const float C2 = 0.08838834764831845f * 1.44269504088896341f; // scale*log2e

    // stage 32-kv tile t into buffer bb: per wave 2 K chunks + 2 V chunks
    auto stage = [&](int bb, int t) {
        const int kb = t * 32;
#pragma unroll
        for (int i = 0; i < 2; ++i) {
            const int c = w * 2 + i;                       // 0..7
            const int kr = c * 4 + (lane >> 4);            // 0..31
            const u32 kcol = (((u32)((lane & 15) * 16)) ^ ((u32)(kr & 7) << 4)) >> 1;
            gload16(Khead + (size_t)(kb + kr) * 6144 + kcol,
                    lK + bb * 4096 + c * 512);
            const int vr = c * 16 + (lane >> 2);           // 0..127
            const u32 vcol = (((u32)((lane & 3) * 16)) ^ ((u32)(vr & 3) << 4)) >> 1;
            gload16(Vth + (size_t)vr * 2048 + kb + vcol,
                    lV + bb * 4096 + c * 512);
        }
    };

    stage(0, t_lo);
    __syncthreads();
    int buf = 0;

    for (int t = t_lo; t < t_hi; ++t) {
        const int kb = t * 32;
        if (t + 1 < t_hi) stage(buf ^ 1, t + 1);

        if (kb <= qw + 31) {
            const char* lKb = (const char*)(lK + buf * 4096);
            const char* lVb = (const char*)(lV + buf * 4096);
            const bool diag = (kb == qw);

            bf16x8 kf[8];
            const u32 ksw = ((u32)ql & 7) << 4;
#pragma unroll
            for (int ch = 0; ch < 8; ++ch)
                kf[ch] = *(const bf16x8*)(lKb + ql * 256 + (((u32)(ch * 32 + g * 16)) ^ ksw));

            f32x16 s_;
#pragma unroll
            for (int r = 0; r < 16; ++r) s_[r] = 0.f;
            __builtin_amdgcn_s_setprio(1);
#pragma unroll
            for (int ch = 0; ch < 8; ++ch)
                s_ = __builtin_amdgcn_mfma_f32_32x32x16_bf16(kf[ch], qf[ch], s_, 0, 0, 0);
            __builtin_amdgcn_s_setprio(0);

            float p[16];
            float tmax = -1e30f;
#pragma unroll
            for (int r = 0; r < 16; ++r) {
                int crow = (r & 3) + 8 * (r >> 2) + 4 * g;
                float v = s_[r];
                if (diag && (crow > ql)) v = -1e30f;   // causal mask
                p[r] = v;
                tmax = fmaxf(tmax, v);
            }
            tmax = fmaxf(tmax, __shfl_xor(tmax, 32));
            if (!__all(tmax <= m_run + 8.0f)) {
                float mnew  = fmaxf(m_run, tmax);
                float alpha = exp2f((m_run - mnew) * C2);
#pragma unroll
                for (int dt = 0; dt < 4; ++dt) acc[dt] = acc[dt] * alpha;
                l_run *= alpha;
                m_run = mnew;
            }
            float ssum = 0.f;
#pragma unroll
            for (int r = 0; r < 16; ++r) {
                float e = exp2f((p[r] - m_run) * C2);
                p[r] = e;
                ssum += e;
            }
            ssum += __shfl_xor(ssum, 32);
            l_run += ssum;

            u32 wb[8], sw[8];
#pragma unroll
            for (int j = 0; j < 8; ++j) wb[j] = pack_bf2(p[2 * j], p[2 * j + 1]);
#pragma unroll
            for (int j = 0; j < 8; ++j) sw[j] = __shfl_xor(wb[j], 32);
            Frag4 pf0, pf1;
#pragma unroll
            for (int u = 0; u < 4; ++u) {
                const bool own = (g == (u >> 1));
                pf0.u[u] = own ? wb[2 * g + (u & 1)]     : sw[2 * g + (u & 1)];
                pf1.u[u] = own ? wb[4 + 2 * g + (u & 1)] : sw[4 + 2 * g + (u & 1)];
            }

            __builtin_amdgcn_s_setprio(1);
#pragma unroll
            for (int dt = 0; dt < 4; ++dt) {
                const u32 vrow = (u32)(dt * 32 + ql);
                const u32 vsw = (vrow & 3) << 4;
                bf16x8 v0 = *(const bf16x8*)(lVb + vrow * 64 + (((u32)(g * 16)) ^ vsw));
                bf16x8 v1 = *(const bf16x8*)(lVb + vrow * 64 + (((u32)(32 + g * 16)) ^ vsw));
                acc[dt] = __builtin_amdgcn_mfma_f32_32x32x16_bf16(v0, pf0.v, acc[dt], 0, 0, 0);
                acc[dt] = __builtin_amdgcn_mfma_f32_32x32x16_bf16(v1, pf1.v, acc[dt], 0, 0, 0);
            }
            __builtin_amdgcn_s_setprio(0);
        }
        __syncthreads();
        buf ^= 1;
    }

    if (slot == 255) {
        const float inv_l = 1.0f / l_run;
        u16* orow = obuf + (rowbase + q) * 2048 + h * 128;
#pragma unroll
        for (int dt = 0; dt < 4; ++dt) {
#pragma unroll
            for (int rr = 0; rr < 4; ++rr) {
                int d0 = dt * 32 + rr * 8 + g * 4;
                int r0 = rr * 4;
                u32 w0 = pack_bf2(acc[dt][r0] * inv_l,     acc[dt][r0 + 1] * inv_l);
                u32 w1 = pack_bf2(acc[dt][r0 + 2] * inv_l, acc[dt][r0 + 3] * inv_l);
                *(u32*)(orow + d0)     = w0;
                *(u32*)(orow + d0 + 2) = w1;
            }
        }
    } else {
        const int sg = bh * 24 + slot;
        const int qloc = w * 32 + ql;
        u16* po = pout + (size_t)sg * 16384 + (size_t)qloc * 128;
#pragma unroll
        for (int dt = 0; dt < 4; ++dt) {
#pragma unroll
            for (int rr = 0; rr < 4; ++rr) {
                int d0 = dt * 32 + rr * 8 + g * 4;
                int r0 = rr * 4;
                u32 w0 = pack_bf2(acc[dt][r0],     acc[dt][r0 + 1]);
                u32 w1 = pack_bf2(acc[dt][r0 + 2], acc[dt][r0 + 3]);
                *(u32*)(po + d0)     = w0;
                *(u32*)(po + d0 + 2) = w1;
            }
        }
        if (g == 0) {
            float2* pm = (float2*)pml + sg * 128 + qloc;
            *pm = make_float2(m_run, l_run);
        }
    }
}

// ---------------- merge the KV-chunk partials (qt >= 6, fan-in 2 or 3) ------
__global__ __launch_bounds__(256) void attn_merge(
    const u16* __restrict__ pout, const float* __restrict__ pml,
    u16* __restrict__ obuf)
{
    const int bid = blockIdx.x;          // 320 = j(10) x bh(32)
    const int bh = bid & 31, j = bid >> 5;
    const int qt = 6 + j;
    const int b = bh >> 4, h = bh & 15;
    const int tid = threadIdx.x;
    const int qloc = tid >> 1, half = (tid & 1) * 64;
    const int f  = (qt < 12) ? 2 : 3;
    const int sb = (qt < 12) ? (qt - 6) * 2 : 12 + (qt - 12) * 3;
    const int base = bh * 24 + sb;
    const float C2 = 0.08838834764831845f * 1.44269504088896341f;

    float mv[3], lv[3], wv[3];
    float ms = -1e30f;
#pragma unroll
    for (int i = 0; i < 3; ++i) {
        if (i < f) {
            float2 ml = ((const float2*)pml)[(base + i) * 128 + qloc];
            mv[i] = ml.x; lv[i] = ml.y;
            ms = fmaxf(ms, ml.x);
        }
    }
    float L = 0.f;
#pragma unroll
    for (int i = 0; i < 3; ++i) {
        if (i < f) {
            wv[i] = exp2f((mv[i] - ms) * C2);
            L += lv[i] * wv[i];
        }
    }
    const float inv = 1.0f / L;

    const int qrow = qt * 128 + qloc;
    u16* orow = obuf + ((size_t)b * 2048 + qrow) * 2048 + h * 128 + half;
#pragma unroll
    for (int j0 = 0; j0 < 64; j0 += 8) {
        float o[8];
#pragma unroll
        for (int e = 0; e < 8; ++e) o[e] = 0.f;
#pragma unroll
        for (int i = 0; i < 3; ++i) {
            if (i < f) {
                bf16x8 v = *(const bf16x8*)(pout + (size_t)(base + i) * 16384
                                            + (size_t)qloc * 128 + half + j0);
#pragma unroll
                for (int e = 0; e < 8; ++e) o[e] += wv[i] * bf2f((u16)v[e]);
            }
        }
#pragma unroll
        for (int e = 0; e < 8; e += 2)
            *(u32*)(orow + j0 + e) = pack_bf2(o[e] * inv, o[e + 1] * inv);
    }
}

extern "C" void kernel_launch(void* const* d_in, const int* in_sizes, int n_in,
                              void* d_out, int out_size, void* d_ws, size_t ws_size,
                              hipStream_t stream) {
    (void)in_sizes; (void)n_in; (void)out_size; (void)ws_size;
    const float* x    = (const float*)d_in[0];
    const float* Wqkv = (const float*)d_in[1];
    const float* bqkv = (const float*)d_in[2];
    const float* Wout = (const float*)d_in[3];
    const float* bout = (const float*)d_in[4];

    char* ws = (char*)d_ws;
    u16* xb  = (u16*)ws;                        // [4096,2048] bf16, 16 MB
    u16* wqb = (u16*)(ws + (size_t)16777216);   // [6144,2048] bf16, 24 MB
    u16* qkv = (u16*)(ws + (size_t)41943040);   // [4096,6144] bf16, 48 MB
    u16* ob  = xb;   // attention out reuses xb (x dead after GEMM1)
    u16* vtb = wqb;  // V^T [32,128,2048] bf16 16 MB reuses wqb
    u16* wob = wqb;  // W_out bf16 reuses wqb again (vtb dead after attn)
    float* pml = (float*)(ws + (size_t)33554432);  // 768KB in wqb tail hole
    u16* pO  = (u16*)d_out;  // 24 MB bf16 partials: d_out is free scratch
                             // until gemm2 overwrites it

    cvt_f32_bf16<<<2048, 256, 0, stream>>>(x, xb, 8388608L / 8);
    cvt_f32_bf16<<<2048, 256, 0, stream>>>(Wqkv, wqb, 12582912L / 8);
    gemm_nt<1><<<1536, 256, 0, stream>>>(xb, wqb, bqkv, qkv, 2048, 6144, 5);
    transpose_v<<<2048, 256, 0, stream>>>(qkv, vtb);
    attn_fwd<<<960, 256, 0, stream>>>(qkv, vtb, ob, pO, pml);
    attn_merge<<<320, 256, 0, stream>>>(pO, pml, ob);
    cvt_f32_bf16<<<2048, 256, 0, stream>>>(Wout, wob, 4194304L / 8);
    gemm_nt<0><<<512, 256, 0, stream>>>(ob, wob, bout, d_out, 2048, 2048, 5);
}

// Round 13
// 299.018 us; speedup vs baseline: 1.5646x; 1.0305x over previous
//
#include <hip/hip_runtime.h>
#include <stdint.h>

typedef short bf16x8 __attribute__((ext_vector_type(8)));
typedef float f32x4 __attribute__((ext_vector_type(4)));
typedef float f32x16 __attribute__((ext_vector_type(16)));
typedef unsigned short u16;
typedef unsigned int u32;

__device__ __forceinline__ u16 f2bf(float f) {
    u32 x = __float_as_uint(f);
    x += 0x7fffu + ((x >> 16) & 1u);
    return (u16)(x >> 16);
}
__device__ __forceinline__ u32 pack_bf2(float a, float b) {
    return (u32)f2bf(a) | ((u32)f2bf(b) << 16);
}
__device__ __forceinline__ float bf2f(u16 v) {
    return __uint_as_float(((u32)v) << 16);
}

union Frag4 { u32 u[4]; bf16x8 v; };

// async global->LDS, 16B per lane; LDS dest is wave-uniform base + lane*16
__device__ __forceinline__ void gload16(const u16* g, u16* l) {
    __builtin_amdgcn_global_load_lds(
        (__attribute__((address_space(1))) void*)g,
        (__attribute__((address_space(3))) void*)l,
        16, 0, 0);
}

// ---------------- f32 -> bf16 cast, 8 elems/thread (G13: vectorized) --------
__global__ void cvt_f32_bf16(const float* __restrict__ in, u16* __restrict__ out, long n8) {
    long stride = (long)gridDim.x * blockDim.x;
    for (long i = (long)blockIdx.x * blockDim.x + threadIdx.x; i < n8; i += stride) {
        const float4* p = (const float4*)(in + i * 8);
        float4 a = p[0], b = p[1];
        uint4 o;
        o.x = pack_bf2(a.x, a.y);
        o.y = pack_bf2(a.z, a.w);
        o.z = pack_bf2(b.x, b.y);
        o.w = pack_bf2(b.z, b.w);
        ((uint4*)out)[i] = o;
    }
}

// ---------------- bf16 NT GEMM: out = A * B^T + bias ------------------------
// 128x128 tile, BK=64, 4 waves, dbuf LDS, T4 counted-vmcnt pipeline
// (stage t+2 after compute t, vmcnt(8) mid-loop). Validated rounds 7-12.
template<int OBF>
__global__ __launch_bounds__(256, 2) void gemm_nt(
    const u16* __restrict__ A, const u16* __restrict__ B,
    const float* __restrict__ bias, void* __restrict__ out,
    int K, int ldo, int gxsh)
{
    __shared__ __align__(16) u16 lA[2 * 128 * 64];
    __shared__ __align__(16) u16 lB[2 * 128 * 64];
    const int tid  = threadIdx.x;
    const int lane = tid & 63;
    const int w    = tid >> 6;
    const int wm = (w >> 1) * 64, wn = (w & 1) * 64;

    const int nwg = gridDim.x;
    const int bid = blockIdx.x;
    const int swz = (bid & 7) * (nwg >> 3) + (bid >> 3);
    const int bm = (swz & ((1 << gxsh) - 1)) * 128;
    const int bn = (swz >> gxsh) * 128;

    const int lr = lane >> 3;
    const u32 sb = (u32)((lane & 7) * 16);
    const int NT = K >> 6;

    auto stage = [&](int bb, int k0) {
#pragma unroll
        for (int i = 0; i < 4; ++i) {
            const int c = w * 4 + i;
            const int row = c * 8 + lr;
            const u32 col = (sb ^ ((u32)(row & 7) << 4)) >> 1;
            gload16(A + (size_t)(bm + row) * K + k0 + col, lA + bb * 8192 + c * 512);
            gload16(B + (size_t)(bn + row) * K + k0 + col, lB + bb * 8192 + c * 512);
        }
    };

    f32x4 acc[4][4];
#pragma unroll
    for (int i = 0; i < 4; ++i)
#pragma unroll
        for (int j = 0; j < 4; ++j)
#pragma unroll
            for (int r = 0; r < 4; ++r) acc[i][j][r] = 0.f;

    stage(0, 0);
    stage(1, 64);
    asm volatile("s_waitcnt vmcnt(8)" ::: "memory");
    __builtin_amdgcn_sched_barrier(0);
    __builtin_amdgcn_s_barrier();
    __builtin_amdgcn_sched_barrier(0);

    for (int t = 0; t < NT; ++t) {
        const int cur = t & 1;
        const char* pA = (const char*)(lA + cur * 8192);
        const char* pB = (const char*)(lB + cur * 8192);
#pragma unroll
        for (int kk = 0; kk < 2; ++kk) {
            bf16x8 af[4], bfr[4];
#pragma unroll
            for (int f = 0; f < 4; ++f) {
                const int m = wm + f * 16 + (lane & 15);
                const u32 byt = (u32)(kk * 64 + (lane >> 4) * 16) ^ ((u32)(m & 7) << 4);
                af[f]  = *(const bf16x8*)(pA + m * 128 + byt);
                const int n = wn + f * 16 + (lane & 15);
                const u32 bytb = (u32)(kk * 64 + (lane >> 4) * 16) ^ ((u32)(n & 7) << 4);
                bfr[f] = *(const bf16x8*)(pB + n * 128 + bytb);
            }
            __builtin_amdgcn_s_setprio(1);
#pragma unroll
            for (int i = 0; i < 4; ++i)
#pragma unroll
                for (int j = 0; j < 4; ++j)
                    acc[i][j] = __builtin_amdgcn_mfma_f32_16x16x32_bf16(af[i], bfr[j], acc[i][j], 0, 0, 0);
            __builtin_amdgcn_s_setprio(0);
        }
        __builtin_amdgcn_sched_barrier(0);
        __builtin_amdgcn_s_barrier();
        __builtin_amdgcn_sched_barrier(0);
        if (t + 2 < NT) {
            stage(cur, (t + 2) * 64);
            asm volatile("s_waitcnt vmcnt(8)" ::: "memory");
        } else {
            asm volatile("s_waitcnt vmcnt(0)" ::: "memory");
        }
        __builtin_amdgcn_sched_barrier(0);
        __builtin_amdgcn_s_barrier();
        __builtin_amdgcn_sched_barrier(0);
    }

#pragma unroll
    for (int i = 0; i < 4; ++i) {
        int m0 = bm + wm + i * 16 + ((lane >> 4) << 2);
#pragma unroll
        for (int j = 0; j < 4; ++j) {
            int n = bn + wn + j * 16 + (lane & 15);
            float bv = bias[n];
#pragma unroll
            for (int r = 0; r < 4; ++r) {
                float v = acc[i][j][r] + bv;
                if constexpr (OBF != 0)
                    ((u16*)out)[(size_t)(m0 + r) * ldo + n] = f2bf(v);
                else
                    ((float*)out)[(size_t)(m0 + r) * ldo + n] = v;
            }
        }
    }
}

// ---------------- V transpose: vt[b,h,d,t] <- qkv[b*2048+t][4096+h*128+d] ---
__global__ __launch_bounds__(256) void transpose_v(
    const u16* __restrict__ qkv, u16* __restrict__ vt)
{
    __shared__ u16 lt[64 * 64];
    const int tid = threadIdx.x;
    const int bid = blockIdx.x;
    const int tt    = bid & 31;
    const int dtile = (bid >> 5) & 1;
    const int h     = (bid >> 6) & 15;
    const int b     = bid >> 10;
    const u16* src = qkv + ((size_t)b * 2048 + tt * 64) * 6144 + 4096 + h * 128 + dtile * 64;

    const int r = tid >> 2, ce = (tid & 3) * 16;
    uint4 a0 = *(const uint4*)(src + (size_t)r * 6144 + ce);
    uint4 a1 = *(const uint4*)(src + (size_t)r * 6144 + ce + 8);
    const u32 swz = (u32)((r & 7) << 4);
    *(uint4*)((char*)lt + r * 128 + (((u32)(ce * 2)) ^ swz)) = a0;
    *(uint4*)((char*)lt + r * 128 + (((u32)(ce * 2 + 16)) ^ swz)) = a1;
    __syncthreads();

    const int d = tid >> 2;
    u16* dst = vt + ((size_t)(b * 16 + h) * 128 + dtile * 64 + d) * 2048 + tt * 64;
#pragma unroll
    for (int it = 0; it < 2; ++it) {
        const int t0 = (tid & 3) * 8 + it * 32;
        union { u16 hh[8]; uint4 q4; } u;
#pragma unroll
        for (int uu = 0; uu < 8; ++uu) {
            int trow = t0 + uu;
            u32 byt = (u32)(trow * 128) + (((u32)(d * 2)) ^ ((u32)((trow & 7) << 4)));
            u.hh[uu] = *(const u16*)((const char*)lt + byt);
        }
        *(uint4*)(dst + t0) = u.q4;
    }
}

// ---------------- causal flash attention (uniform-chunk KV-split) -----------
// Round-12 validated inner loop and tables. NEW: epilogue routes O through
// LDS (dead staging buffer) so global stores are coalesced 16B/lane rows
// instead of 64-line scatters (fixes 102MB->~33MB WRITE amplification).
__constant__ unsigned char QT_TAB[30] = {11,11, 5,15,15,15,10,10,14,14,14, 9, 9, 4,13,13,13,12,12,12, 8, 8, 7, 7, 3, 6, 6, 2, 1, 0};
__constant__ unsigned char TLO_TAB[30]= { 0,24, 0, 0,22,43, 0,22, 0,20,40, 0,20, 0, 0,19,38, 0,18,36, 0,18, 0,16, 0, 0,14, 0, 0, 0};
__constant__ unsigned char THI_TAB[30]= {24,48,24,22,43,64,22,44,20,40,60,20,40,20,19,38,56,18,36,52,18,36,16,32,16,14,28,12, 8, 4};
__constant__ unsigned char SL_TAB[30] = {10,11,255,21,22,23, 8, 9,18,19,20, 6, 7,255,15,16,17,12,13,14, 4, 5, 2, 3,255, 0, 1,255,255,255};

__global__ __launch_bounds__(256) void attn_fwd(
    const u16* __restrict__ qkv, const u16* __restrict__ vt,
    u16* __restrict__ obuf, u16* __restrict__ pout, float* __restrict__ pml)
{
    // staging: K(buf b) at lS + b*4096, V(buf b) at lS + 8192 + b*4096
    // epilogue: wave w private region lS + w*4352 (32 rows x 136 elems)
    __shared__ __align__(16) u16 lS[17408];
    const int tid  = threadIdx.x;
    const int lane = tid & 63;
    const int w    = tid >> 6;
    const int g    = lane >> 5;
    const int ql   = lane & 31;

    const int bid  = blockIdx.x;
    const int item = bid >> 5;
    const int bh   = bid & 31;
    const int qt   = QT_TAB[item];
    const int slot = SL_TAB[item];
    const int t_lo = TLO_TAB[item];
    const int t_hi = THI_TAB[item];
    const int b = bh >> 4, h = bh & 15;
    const size_t rowbase = (size_t)b * 2048;
    const int qb = qt * 128;
    const int qw = qb + w * 32;
    const int q  = qw + ql;

    const u16* Khead = qkv + rowbase * 6144 + 2048 + h * 128;  // ld 6144
    const u16* Vth   = vt + (size_t)bh * 128 * 2048;           // Vt[d][t]

    bf16x8 qf[8];
    {
        const u16* qrow = qkv + (rowbase + q) * 6144 + h * 128;
#pragma unroll
        for (int ch = 0; ch < 8; ++ch)
            qf[ch] = *(const bf16x8*)(qrow + ch * 16 + g * 8);
    }

    f32x16 acc[4];
#pragma unroll
    for (int dt = 0; dt < 4; ++dt)
#pragma unroll
        for (int r = 0; r < 16; ++r) acc[dt][r] = 0.f;

    float m_run = -1e30f, l_run = 0.f;
    const float C2 = 0.08838834764831845f * 1.44269504088896341f; // scale*log2e

    // stage 32-kv tile t into buffer bb: per wave 2 K chunks + 2 V chunks
    auto stage = [&](int bb, int t) {
        const int kb = t * 32;
#pragma unroll
        for (int i = 0; i < 2; ++i) {
            const int c = w * 2 + i;                       // 0..7
            const int kr = c * 4 + (lane >> 4);            // 0..31
            const u32 kcol = (((u32)((lane & 15) * 16)) ^ ((u32)(kr & 7) << 4)) >> 1;
            gload16(Khead + (size_t)(kb + kr) * 6144 + kcol,
                    lS + bb * 4096 + c * 512);
            const int vr = c * 16 + (lane >> 2);           // 0..127
            const u32 vcol = (((u32)((lane & 3) * 16)) ^ ((u32)(vr & 3) << 4)) >> 1;
            gload16(Vth + (size_t)vr * 2048 + kb + vcol,
                    lS + 8192 + bb * 4096 + c * 512);
        }
    };

    stage(0, t_lo);
    __syncthreads();
    int buf = 0;

    for (int t = t_lo; t < t_hi; ++t) {
        const int kb = t * 32;
        if (t + 1 < t_hi) stage(buf ^ 1, t + 1);

        if (kb <= qw + 31) {
            const char* lKb = (const char*)(lS + buf * 4096);
            const char* lVb = (const char*)(lS + 8192 + buf * 4096);
            const bool diag = (kb == qw);

            bf16x8 kf[8];
            const u32 ksw = ((u32)ql & 7) << 4;
#pragma unroll
            for (int ch = 0; ch < 8; ++ch)
                kf[ch] = *(const bf16x8*)(lKb + ql * 256 + (((u32)(ch * 32 + g * 16)) ^ ksw));

            f32x16 s_;
#pragma unroll
            for (int r = 0; r < 16; ++r) s_[r] = 0.f;
            __builtin_amdgcn_s_setprio(1);
#pragma unroll
            for (int ch = 0; ch < 8; ++ch)
                s_ = __builtin_amdgcn_mfma_f32_32x32x16_bf16(kf[ch], qf[ch], s_, 0, 0, 0);
            __builtin_amdgcn_s_setprio(0);

            float p[16];
            float tmax = -1e30f;
#pragma unroll
            for (int r = 0; r < 16; ++r) {
                int crow = (r & 3) + 8 * (r >> 2) + 4 * g;
                float v = s_[r];
                if (diag && (crow > ql)) v = -1e30f;   // causal mask
                p[r] = v;
                tmax = fmaxf(tmax, v);
            }
            tmax = fmaxf(tmax, __shfl_xor(tmax, 32));
            if (!__all(tmax <= m_run + 8.0f)) {
                float mnew  = fmaxf(m_run, tmax);
                float alpha = exp2f((m_run - mnew) * C2);
#pragma unroll
                for (int dt = 0; dt < 4; ++dt) acc[dt] = acc[dt] * alpha;
                l_run *= alpha;
                m_run = mnew;
            }
            float ssum = 0.f;
#pragma unroll
            for (int r = 0; r < 16; ++r) {
                float e = exp2f((p[r] - m_run) * C2);
                p[r] = e;
                ssum += e;
            }
            ssum += __shfl_xor(ssum, 32);
            l_run += ssum;

            u32 wb[8], sw[8];
#pragma unroll
            for (int j = 0; j < 8; ++j) wb[j] = pack_bf2(p[2 * j], p[2 * j + 1]);
#pragma unroll
            for (int j = 0; j < 8; ++j) sw[j] = __shfl_xor(wb[j], 32);
            Frag4 pf0, pf1;
#pragma unroll
            for (int u = 0; u < 4; ++u) {
                const bool own = (g == (u >> 1));
                pf0.u[u] = own ? wb[2 * g + (u & 1)]     : sw[2 * g + (u & 1)];
                pf1.u[u] = own ? wb[4 + 2 * g + (u & 1)] : sw[4 + 2 * g + (u & 1)];
            }

            __builtin_amdgcn_s_setprio(1);
#pragma unroll
            for (int dt = 0; dt < 4; ++dt) {
                const u32 vrow = (u32)(dt * 32 + ql);
                const u32 vsw = (vrow & 3) << 4;
                bf16x8 v0 = *(const bf16x8*)(lVb + vrow * 64 + (((u32)(g * 16)) ^ vsw));
                bf16x8 v1 = *(const bf16x8*)(lVb + vrow * 64 + (((u32)(32 + g * 16)) ^ vsw));
                acc[dt] = __builtin_amdgcn_mfma_f32_32x32x16_bf16(v0, pf0.v, acc[dt], 0, 0, 0);
                acc[dt] = __builtin_amdgcn_mfma_f32_32x32x16_bf16(v1, pf1.v, acc[dt], 0, 0, 0);
            }
            __builtin_amdgcn_s_setprio(0);
        }
        __syncthreads();
        buf ^= 1;
    }

    // ---------------- epilogue: O via LDS for coalesced global stores -------
    // lane ql owns q-row ql of this wave; write its 32 O-values (pre-scaled
    // for the direct path) into the wave-private [32][136] region, then read
    // back 4 rows/pass and store 16B/lane coalesced.
    const float scale = (slot == 255) ? (1.0f / l_run) : 1.0f;
    u16* lO = lS + w * 4352;
#pragma unroll
    for (int dt = 0; dt < 4; ++dt) {
#pragma unroll
        for (int rr = 0; rr < 4; ++rr) {
            int d0 = dt * 32 + rr * 8 + g * 4;
            int r0 = rr * 4;
            u32* dst = (u32*)(lO + ql * 136 + d0);
            dst[0] = pack_bf2(acc[dt][r0] * scale,     acc[dt][r0 + 1] * scale);
            dst[1] = pack_bf2(acc[dt][r0 + 2] * scale, acc[dt][r0 + 3] * scale);
        }
    }
    if (slot != 255 && g == 0) {
        const int sg = bh * 24 + slot;
        float2* pm = (float2*)pml + sg * 128 + (w * 32 + ql);
        *pm = make_float2(m_run, l_run);
    }
    __syncthreads();

    u16* gbase;
    size_t rstride;
    if (slot == 255) {
        gbase = obuf + (rowbase + qw) * 2048 + h * 128;
        rstride = 2048;
    } else {
        const int sg = bh * 24 + slot;
        gbase = pout + (size_t)sg * 16384 + (size_t)(w * 32) * 128;
        rstride = 128;
    }
    const int eo = (lane & 15) * 8;
#pragma unroll
    for (int pass = 0; pass < 8; ++pass) {
        const int row = pass * 4 + (lane >> 4);
        bf16x8 v = *(const bf16x8*)(lO + row * 136 + eo);
        *(bf16x8*)(gbase + (size_t)row * rstride + eo) = v;
    }
}

// ---------------- merge the KV-chunk partials (qt >= 6, fan-in 2 or 3) ------
// Coalesced mapping: thread -> 16 contiguous bytes; 16 rows/pass, 8 passes.
__global__ __launch_bounds__(256) void attn_merge(
    const u16* __restrict__ pout, const float* __restrict__ pml,
    u16* __restrict__ obuf)
{
    const int bid = blockIdx.x;          // 320 = j(10) x bh(32)
    const int bh = bid & 31, j = bid >> 5;
    const int qt = 6 + j;
    const int b = bh >> 4, h = bh & 15;
    const int tid = threadIdx.x;
    const int f  = (qt < 12) ? 2 : 3;
    const int sb = (qt < 12) ? (qt - 6) * 2 : 12 + (qt - 12) * 3;
    const int base = bh * 24 + sb;
    const float C2 = 0.08838834764831845f * 1.44269504088896341f;
    const int eo = (tid & 15) * 8;

#pragma unroll
    for (int pass = 0; pass < 8; ++pass) {
        const int row = pass * 16 + (tid >> 4);   // qloc 0..127
        float mv[3], lv[3], wv[3];
        float ms = -1e30f;
#pragma unroll
        for (int i = 0; i < 3; ++i) {
            if (i < f) {
                float2 ml = ((const float2*)pml)[(base + i) * 128 + row];
                mv[i] = ml.x; lv[i] = ml.y;
                ms = fmaxf(ms, ml.x);
            }
        }
        float L = 0.f;
#pragma unroll
        for (int i = 0; i < 3; ++i) {
            if (i < f) {
                wv[i] = exp2f((mv[i] - ms) * C2);
                L += lv[i] * wv[i];
            }
        }
        const float inv = 1.0f / L;

        float o[8];
#pragma unroll
        for (int e = 0; e < 8; ++e) o[e] = 0.f;
#pragma unroll
        for (int i = 0; i < 3; ++i) {
            if (i < f) {
                bf16x8 v = *(const bf16x8*)(pout + (size_t)(base + i) * 16384
                                            + (size_t)row * 128 + eo);
#pragma unroll
                for (int e = 0; e < 8; ++e) o[e] += wv[i] * bf2f((u16)v[e]);
            }
        }
        u16* orow = obuf + ((size_t)b * 2048 + qt * 128 + row) * 2048 + h * 128 + eo;
#pragma unroll
        for (int e = 0; e < 8; e += 2)
            *(u32*)(orow + e) = pack_bf2(o[e] * inv, o[e + 1] * inv);
    }
}

extern "C" void kernel_launch(void* const* d_in, const int* in_sizes, int n_in,
                              void* d_out, int out_size, void* d_ws, size_t ws_size,
                              hipStream_t stream) {
    (void)in_sizes; (void)n_in; (void)out_size; (void)ws_size;
    const float* x    = (const float*)d_in[0];
    const float* Wqkv = (const float*)d_in[1];
    const float* bqkv = (const float*)d_in[2];
    const float* Wout = (const float*)d_in[3];
    const float* bout = (const float*)d_in[4];

    char* ws = (char*)d_ws;
    u16* xb  = (u16*)ws;                        // [4096,2048] bf16, 16 MB
    u16* wqb = (u16*)(ws + (size_t)16777216);   // [6144,2048] bf16, 24 MB
    u16* qkv = (u16*)(ws + (size_t)41943040);   // [4096,6144] bf16, 48 MB
    u16* ob  = xb;   // attention out reuses xb (x dead after GEMM1)
    u16* vtb = wqb;  // V^T [32,128,2048] bf16 16 MB reuses wqb
    u16* wob = wqb;  // W_out bf16 reuses wqb again (vtb dead after attn)
    float* pml = (float*)(ws + (size_t)33554432);  // 768KB in wqb tail hole
    u16* pO  = (u16*)d_out;  // 24 MB bf16 partials: d_out is free scratch
                             // until gemm2 overwrites it

    cvt_f32_bf16<<<2048, 256, 0, stream>>>(x, xb, 8388608L / 8);
    cvt_f32_bf16<<<2048, 256, 0, stream>>>(Wqkv, wqb, 12582912L / 8);
    gemm_nt<1><<<1536, 256, 0, stream>>>(xb, wqb, bqkv, qkv, 2048, 6144, 5);
    transpose_v<<<2048, 256, 0, stream>>>(qkv, vtb);
    attn_fwd<<<960, 256, 0, stream>>>(qkv, vtb, ob, pO, pml);
    attn_merge<<<320, 256, 0, stream>>>(pO, pml, ob);
    cvt_f32_bf16<<<2048, 256, 0, stream>>>(Wout, wob, 4194304L / 8);
    gemm_nt<0><<<512, 256, 0, stream>>>(ob, wob, bout, d_out, 2048, 2048, 5);
}